// Round 13
// baseline (408.737 us; speedup 1.0000x reference)
//
#include <hip/hip_runtime.h>
#include <cstdint>

typedef unsigned short u16;
typedef unsigned int u32;
typedef __attribute__((ext_vector_type(8))) short bf16x8;
typedef __attribute__((ext_vector_type(4))) float f32x4;

typedef const u32 __attribute__((address_space(1)))* gp_t;
typedef u32 __attribute__((address_space(3)))* lp_t;

__device__ __forceinline__ u16 f2bf(float f) {
    union { float f; u32 u; } v; v.f = f;
    u32 r = v.u + 0x7FFFu + ((v.u >> 16) & 1u);   // RNE
    return (u16)(r >> 16);
}
__device__ __forceinline__ float bf2f(u16 h) {
    union { u32 u; float f; } v; v.u = ((u32)h) << 16;
    return v.f;
}

// ---------------- pack x -> xt (token-major bf16) + xc (channel-major bf16) ----
__global__ __launch_bounds__(256) void k_pack2(const float* __restrict__ x,
                                               u16* __restrict__ xt, u16* __restrict__ xc) {
    __shared__ u16 tb[64][72];
    const int blk = blockIdx.x;
    const int tt = blk >> 4, ct = blk & 15;
    const long tok0 = (long)tt * 64;
    const int ch0 = ct * 64;
    const int tid = threadIdx.x;
    const int row = tid >> 2, cq = tid & 3;
#pragma unroll
    for (int jj = 0; jj < 4; ++jj) {
        const float4 v = *(const float4*)(x + (tok0 + row) * 1024 + ch0 + cq * 16 + jj * 4);
        tb[row][cq * 16 + jj * 4 + 0] = f2bf(v.x);
        tb[row][cq * 16 + jj * 4 + 1] = f2bf(v.y);
        tb[row][cq * 16 + jj * 4 + 2] = f2bf(v.z);
        tb[row][cq * 16 + jj * 4 + 3] = f2bf(v.w);
    }
    __syncthreads();
#pragma unroll
    for (int s = 0; s < 2; ++s) {
        const int c = s * 256 + tid;
        const int r2 = c >> 3, col8 = c & 7;
        *(uint4*)(xt + (tok0 + r2) * 1024 + ch0 + col8 * 8) = *(const uint4*)(&tb[r2][col8 * 8]);
    }
    const int b = (int)(tok0 >> 12);
    const int nin = (int)(tok0 & 4095);
#pragma unroll
    for (int s = 0; s < 2; ++s) {
        const int c = s * 256 + tid;
        const int crow = c >> 3, t8 = c & 7;
        u16 u[8];
#pragma unroll
        for (int k = 0; k < 8; ++k) u[k] = tb[t8 * 8 + k][crow];
        *(uint4*)(xc + ((long)b * 1024 + ch0 + crow) * 4096 + nin + t8 * 8) = *(const uint4*)u;
    }
}

// ---------------- fused prep: wqT transpose / wpT transpose / wvb pack ----------
__global__ __launch_bounds__(256) void k_prep(
    const float* __restrict__ wqkv, const float* __restrict__ wproj,
    u16* __restrict__ wqT, u16* __restrict__ wpT, u16* __restrict__ wvb)
{
    __shared__ float t[64][65];
    const int blk = blockIdx.x;
    const int tid = threadIdx.x;
    if (blk < 1024) {
        const float* src; u16* dst; int ncols, lb;
        if (blk < 768) { src = wqkv; dst = wqT; ncols = 3072; lb = blk; }
        else           { src = wproj; dst = wpT; ncols = 1024; lb = blk - 768; }
        const int ntn = ncols >> 6;
        const int kb = (lb / ntn) * 64;
        const int nb = (lb % ntn) * 64;
        for (int i = tid; i < 4096; i += 256) {
            int r = i >> 6, c = i & 63;
            t[r][c] = src[(long)(kb + r) * ncols + nb + c];
        }
        __syncthreads();
        for (int i = tid; i < 4096; i += 256) {
            int r = i >> 6, c = i & 63;
            dst[(long)(nb + r) * 1024 + kb + c] = f2bf(t[c][r]);
        }
    } else {
        const int idx = (blk - 1024) * 256 + tid;   // [0, 131072)
        const int cin = idx >> 7, e0 = (idx & 127) * 8;
        const float4 v1 = *(const float4*)(wqkv + (long)cin * 3072 + 2048 + e0);
        const float4 v2 = *(const float4*)(wqkv + (long)cin * 3072 + 2048 + e0 + 4);
        u16 u[8];
        u[0] = f2bf(v1.x); u[1] = f2bf(v1.y); u[2] = f2bf(v1.z); u[3] = f2bf(v1.w);
        u[4] = f2bf(v2.x); u[5] = f2bf(v2.y); u[6] = f2bf(v2.z); u[7] = f2bf(v2.w);
        *(uint4*)(wvb + (long)cin * 1024 + e0) = *(const uint4*)u;
    }
}

// ---------------- S partials: 128x128 tile x K=1024 segment of xc_b @ xc_b^T -----
__global__ __launch_bounds__(256) void k_g128p(
    const u16* __restrict__ xc, float* __restrict__ Sp)
{
    __shared__ u16 sm[8192];

    const int tid = threadIdx.x;
    const int wid = tid >> 6, lane = tid & 63;
    const int wr = wid >> 1, wc = wid & 1;
    const int fr = lane & 15, sl = lane >> 4;

    const int nwg = gridDim.x;
    const int logical = (blockIdx.x & 7) * (nwg >> 3) + (blockIdx.x >> 3);
    const int kseg = logical & 3;
    const int bt = logical >> 2;
    const int b = bt / 36;
    int t = bt % 36;
    int i0 = 0;
    while (t >= 8 - i0) { t -= 8 - i0; ++i0; }
    const int j0 = i0 + t;
    const int m0 = i0 * 128, n0 = j0 * 128;

    const u16* base = xc + (long)b * 4194304 + kseg * 1024;

    const int srow = lane >> 2;
    const int sslot = lane & 3;

    f32x4 acc[4][4];
#pragma unroll
    for (int i = 0; i < 4; ++i)
#pragma unroll
        for (int j = 0; j < 4; ++j) acc[i][j] = (f32x4){0.f, 0.f, 0.f, 0.f};

    for (int kt = 0; kt < 1024; kt += 32) {
        __syncthreads();
#pragma unroll
        for (int i = 0; i < 2; ++i) {
            const int row = wid * 32 + i * 16 + srow;
            const int swz = (sslot ^ ((row >> 1) & 3)) << 3;
            const u16* ga = base + (long)(m0 + row) * 4096 + kt + swz;
            const u16* gb = base + (long)(n0 + row) * 4096 + kt + swz;
            __builtin_amdgcn_global_load_lds((gp_t)ga, (lp_t)(sm + (wid * 2 + i) * 512), 16, 0, 0);
            __builtin_amdgcn_global_load_lds((gp_t)gb, (lp_t)(sm + 4096 + (wid * 2 + i) * 512), 16, 0, 0);
        }
        __syncthreads();
        bf16x8 af[4], bfr[4];
#pragma unroll
        for (int mi = 0; mi < 4; ++mi) {
            const int row = wr * 64 + mi * 16 + fr;
            af[mi] = *(const bf16x8*)(sm + row * 32 + ((sl ^ ((row >> 1) & 3)) << 3));
        }
#pragma unroll
        for (int ni = 0; ni < 4; ++ni) {
            const int row = wc * 64 + ni * 16 + fr;
            bfr[ni] = *(const bf16x8*)(sm + 4096 + row * 32 + ((sl ^ ((row >> 1) & 3)) << 3));
        }
#pragma unroll
        for (int mi = 0; mi < 4; ++mi)
#pragma unroll
            for (int ni = 0; ni < 4; ++ni)
                acc[mi][ni] = __builtin_amdgcn_mfma_f32_16x16x32_bf16(af[mi], bfr[ni], acc[mi][ni], 0, 0, 0);
    }

    float* gp = Sp + (long)logical * 16384;
#pragma unroll
    for (int mi = 0; mi < 4; ++mi)
#pragma unroll
        for (int ni = 0; ni < 4; ++ni)
#pragma unroll
            for (int rr = 0; rr < 4; ++rr)
                gp[(wr * 64 + mi * 16 + sl * 4 + rr) * 128 + wc * 64 + ni * 16 + fr] = acc[mi][ni][rr];
}

// ---------------- reduce 4 S partials -> bf16 S, row-major + transposed ----------
__global__ __launch_bounds__(256) void k_sred(const float* __restrict__ Sp, u16* __restrict__ S)
{
    __shared__ u16 lC[128 * 136];
    __shared__ u16 lCT[128 * 136];

    const int tid = threadIdx.x;
    const int nwg = gridDim.x;               // 288
    const int logical = (blockIdx.x & 7) * (nwg >> 3) + (blockIdx.x >> 3);
    const int b = logical / 36;
    int t = logical % 36;
    int i0 = 0;
    while (t >= 8 - i0) { t -= 8 - i0; ++i0; }
    const int j0 = i0 + t;
    const int m0 = i0 * 128, n0 = j0 * 128;

    const float* p = Sp + (long)logical * 65536;
    for (int i = tid; i < 16384; i += 256) {
        const float s = p[i] + p[i + 16384] + p[i + 32768] + p[i + 49152];
        const u16 v = f2bf(s);
        const int r_ = i >> 7, c_ = i & 127;
        lC[r_ * 136 + c_] = v;
        lCT[c_ * 136 + r_] = v;
    }
    __syncthreads();
    const int tk = tid >> 1, half = tid & 1;
    {
        u16* dp = S + (long)b * 1048576 + (long)(m0 + tk) * 1024 + n0 + half * 64;
        const u16* sp1 = lC + tk * 136 + half * 64;
#pragma unroll
        for (int i = 0; i < 8; ++i) ((uint4*)dp)[i] = ((const uint4*)sp1)[i];
    }
    if (i0 != j0) {
        u16* dp = S + (long)b * 1048576 + (long)(n0 + tk) * 1024 + m0 + half * 64;
        const u16* sp2 = lCT + tk * 136 + half * 64;
#pragma unroll
        for (int i = 0; i < 8; ++i) ((uint4*)dp)[i] = ((const uint4*)sp2)[i];
    }
}

// ---------------- 128x128 GEMM, BK=32, batched, bf16 out (pitch 1024) ------------
__global__ __launch_bounds__(256) void k_g128(
    const u16* __restrict__ A, long Ab, const u16* __restrict__ Bt, long Bs,
    u16* __restrict__ C, long Cb, int K, int MT, int NT)
{
    __shared__ u16 sm[8192];
    __shared__ u16 lC[128 * 136];

    const int tid = threadIdx.x;
    const int wid = tid >> 6, lane = tid & 63;
    const int wr = wid >> 1, wc = wid & 1;
    const int fr = lane & 15, sl = lane >> 4;

    const int nwg = gridDim.x;
    const int logical = (blockIdx.x & 7) * (nwg >> 3) + (blockIdx.x >> 3);

    const int b = logical / (MT * NT);
    const int r = logical % (MT * NT);
    const int i0 = r / NT, j0 = r % NT;
    const int m0 = i0 * 128, n0 = j0 * 128;
    const u16* Abp = A + (long)b * Ab;
    const u16* Bbp = Bt + (long)b * Bs;
    u16* Cbp = C + (long)b * Cb;

    const int srow = lane >> 2;
    const int sslot = lane & 3;

    f32x4 acc[4][4];
#pragma unroll
    for (int i = 0; i < 4; ++i)
#pragma unroll
        for (int j = 0; j < 4; ++j) acc[i][j] = (f32x4){0.f, 0.f, 0.f, 0.f};

    for (int kt = 0; kt < K; kt += 32) {
        __syncthreads();
#pragma unroll
        for (int i = 0; i < 2; ++i) {
            const int row = wid * 32 + i * 16 + srow;
            const int swz = (sslot ^ ((row >> 1) & 3)) << 3;
            const u16* ga = Abp + (long)(m0 + row) * K + kt + swz;
            const u16* gb = Bbp + (long)(n0 + row) * K + kt + swz;
            __builtin_amdgcn_global_load_lds((gp_t)ga, (lp_t)(sm + (wid * 2 + i) * 512), 16, 0, 0);
            __builtin_amdgcn_global_load_lds((gp_t)gb, (lp_t)(sm + 4096 + (wid * 2 + i) * 512), 16, 0, 0);
        }
        __syncthreads();
        bf16x8 af[4], bfr[4];
#pragma unroll
        for (int mi = 0; mi < 4; ++mi) {
            const int row = wr * 64 + mi * 16 + fr;
            af[mi] = *(const bf16x8*)(sm + row * 32 + ((sl ^ ((row >> 1) & 3)) << 3));
        }
#pragma unroll
        for (int ni = 0; ni < 4; ++ni) {
            const int row = wc * 64 + ni * 16 + fr;
            bfr[ni] = *(const bf16x8*)(sm + 4096 + row * 32 + ((sl ^ ((row >> 1) & 3)) << 3));
        }
#pragma unroll
        for (int mi = 0; mi < 4; ++mi)
#pragma unroll
            for (int ni = 0; ni < 4; ++ni)
                acc[mi][ni] = __builtin_amdgcn_mfma_f32_16x16x32_bf16(af[mi], bfr[ni], acc[mi][ni], 0, 0, 0);
    }
    __syncthreads();

#pragma unroll
    for (int mi = 0; mi < 4; ++mi)
#pragma unroll
        for (int ni = 0; ni < 4; ++ni) {
            const int ch = wc * 64 + ni * 16 + fr;
            const int tk = wr * 64 + mi * 16 + sl * 4;
#pragma unroll
            for (int rr = 0; rr < 4; ++rr)
                lC[(tk + rr) * 136 + ch] = f2bf(acc[mi][ni][rr]);
        }
    __syncthreads();
    {
        const int tk = tid >> 1, half = tid & 1;
        const u16* sp = lC + tk * 136 + half * 64;
        u16* dp = Cbp + (long)(m0 + tk) * 1024 + n0 + half * 64;
#pragma unroll
        for (int i = 0; i < 8; ++i) ((uint4*)dp)[i] = ((const uint4*)sp)[i];
    }
}

// ---------------- 128x128 GEMM, BK=32, batched, f32+bias out (final) -------------
__global__ __launch_bounds__(256) void k_g128f(
    const u16* __restrict__ A, long Ab, const u16* __restrict__ Bt, long Bs,
    float* __restrict__ C, long Cb, int K, int MT, int NT, const float* __restrict__ bias)
{
    __shared__ u16 sm[8192];
    __shared__ float lCf[4 * 2176];          // 4 wave-pieces x [32 rows][pitch 68] f32

    const int tid = threadIdx.x;
    const int wid = tid >> 6, lane = tid & 63;
    const int wr = wid >> 1, wc = wid & 1;
    const int fr = lane & 15, sl = lane >> 4;

    const int nwg = gridDim.x;
    const int logical = (blockIdx.x & 7) * (nwg >> 3) + (blockIdx.x >> 3);

    const int b = logical / (MT * NT);
    const int r = logical % (MT * NT);
    const int i0 = r / NT, j0 = r % NT;
    const int m0 = i0 * 128, n0 = j0 * 128;
    const u16* Abp = A + (long)b * Ab;
    const u16* Bbp = Bt + (long)b * Bs;
    float* Cbp = C + (long)b * Cb;

    const int srow = lane >> 2;
    const int sslot = lane & 3;

    f32x4 acc[4][4];
#pragma unroll
    for (int i = 0; i < 4; ++i)
#pragma unroll
        for (int j = 0; j < 4; ++j) acc[i][j] = (f32x4){0.f, 0.f, 0.f, 0.f};

    for (int kt = 0; kt < K; kt += 32) {
        __syncthreads();
#pragma unroll
        for (int i = 0; i < 2; ++i) {
            const int row = wid * 32 + i * 16 + srow;
            const int swz = (sslot ^ ((row >> 1) & 3)) << 3;
            const u16* ga = Abp + (long)(m0 + row) * K + kt + swz;
            const u16* gb = Bbp + (long)(n0 + row) * K + kt + swz;
            __builtin_amdgcn_global_load_lds((gp_t)ga, (lp_t)(sm + (wid * 2 + i) * 512), 16, 0, 0);
            __builtin_amdgcn_global_load_lds((gp_t)gb, (lp_t)(sm + 4096 + (wid * 2 + i) * 512), 16, 0, 0);
        }
        __syncthreads();
        bf16x8 af[4], bfr[4];
#pragma unroll
        for (int mi = 0; mi < 4; ++mi) {
            const int row = wr * 64 + mi * 16 + fr;
            af[mi] = *(const bf16x8*)(sm + row * 32 + ((sl ^ ((row >> 1) & 3)) << 3));
        }
#pragma unroll
        for (int ni = 0; ni < 4; ++ni) {
            const int row = wc * 64 + ni * 16 + fr;
            bfr[ni] = *(const bf16x8*)(sm + 4096 + row * 32 + ((sl ^ ((row >> 1) & 3)) << 3));
        }
#pragma unroll
        for (int mi = 0; mi < 4; ++mi)
#pragma unroll
            for (int ni = 0; ni < 4; ++ni)
                acc[mi][ni] = __builtin_amdgcn_mfma_f32_16x16x32_bf16(af[mi], bfr[ni], acc[mi][ni], 0, 0, 0);
    }
    __syncthreads();

    float bi[4];
#pragma unroll
    for (int ni = 0; ni < 4; ++ni) bi[ni] = bias[n0 + wc * 64 + ni * 16 + fr];

#pragma unroll
    for (int pass = 0; pass < 2; ++pass) {
        if (pass) __syncthreads();
        float* piece = lCf + (wr * 2 + wc) * 2176;
#pragma unroll
        for (int mi2 = 0; mi2 < 2; ++mi2) {
            const int mi = pass * 2 + mi2;
#pragma unroll
            for (int ni = 0; ni < 4; ++ni)
#pragma unroll
                for (int rr = 0; rr < 4; ++rr)
                    piece[(mi2 * 16 + sl * 4 + rr) * 68 + ni * 16 + fr] = acc[mi][ni][rr] + bi[ni];
        }
        __syncthreads();
        // copy 64 rows x 128 f32 (2048 float4 chunks)
#pragma unroll
        for (int i = 0; i < 8; ++i) {
            const int chunk = i * 256 + tid;
            const int lr = chunk >> 5, c4 = chunk & 31;
            const int wrp = lr >> 5, r32 = lr & 31;
            const int wcp = c4 >> 4;
            const float4 v = *(const float4*)(lCf + (wrp * 2 + wcp) * 2176 + r32 * 68 + (c4 & 15) * 4);
            *(float4*)(Cbp + (long)(m0 + wrp * 64 + pass * 32 + r32) * 1024 + n0 + wcp * 64 + (c4 & 15) * 4) = v;
        }
    }
}

// ---------------- gram partials per (b,h,kseg): 64x64 Gram + 128 row-dots --------
__global__ __launch_bounds__(256) void k_gram2p(
    const u16* __restrict__ wqT, const u16* __restrict__ Ut,
    float* __restrict__ g2p, float* __restrict__ sq2p)
{
    __shared__ u16 lQ[64 * 256];
    __shared__ u16 lK[64 * 256];

    const int blk = blockIdx.x;           // bh*4 + seg
    const int seg = blk & 3, bh = blk >> 2;
    const int b = bh >> 4, h = bh & 15;
    const int tid = threadIdx.x;
    const int wid = tid >> 6, lane = tid & 63;

    {
        const int r2 = lane >> 5, slot = lane & 31;
        const int rbase = wid * 16;
#pragma unroll
        for (int i = 0; i < 8; ++i) {
            const int r = rbase + i * 2 + r2;
            const int col = seg * 256 + ((slot ^ (r & 7)) << 3);
            const u16* gq = wqT + (long)(h * 64 + r) * 1024 + col;
            const u16* gk = Ut + ((long)b * 2048 + 1024 + h * 64 + r) * 1024 + col;
            __builtin_amdgcn_global_load_lds((gp_t)gq, (lp_t)(lQ + (rbase + i * 2) * 256), 16, 0, 0);
            __builtin_amdgcn_global_load_lds((gp_t)gk, (lp_t)(lK + (rbase + i * 2) * 256), 16, 0, 0);
        }
    }
    __syncthreads();

    {
        const int row = tid >> 1, half = tid & 1;
        const int j = (row < 64) ? (h * 64 + row) : (1024 + h * 64 + (row - 64));
        const u16* pa = wqT + (long)j * 1024 + seg * 256 + half * 128;
        const u16* pb = Ut + ((long)b * 2048 + j) * 1024 + seg * 256 + half * 128;
        float s = 0.f;
#pragma unroll 4
        for (int i = 0; i < 16; ++i) {
            const uint4 a = *(const uint4*)(pa + i * 8);
            const uint4 bv = *(const uint4*)(pb + i * 8);
            s += bf2f((u16)(a.x & 0xFFFF)) * bf2f((u16)(bv.x & 0xFFFF));
            s += bf2f((u16)(a.x >> 16))    * bf2f((u16)(bv.x >> 16));
            s += bf2f((u16)(a.y & 0xFFFF)) * bf2f((u16)(bv.y & 0xFFFF));
            s += bf2f((u16)(a.y >> 16))    * bf2f((u16)(bv.y >> 16));
            s += bf2f((u16)(a.z & 0xFFFF)) * bf2f((u16)(bv.z & 0xFFFF));
            s += bf2f((u16)(a.z >> 16))    * bf2f((u16)(bv.z >> 16));
            s += bf2f((u16)(a.w & 0xFFFF)) * bf2f((u16)(bv.w & 0xFFFF));
            s += bf2f((u16)(a.w >> 16))    * bf2f((u16)(bv.w >> 16));
        }
        s += __shfl_xor(s, 1);
        if (half == 0) sq2p[(long)blk * 128 + row] = s;
    }

    const int fr = lane & 15, sl = lane >> 4;
    f32x4 acc[4];
#pragma unroll
    for (int i = 0; i < 4; ++i) acc[i] = (f32x4){0.f, 0.f, 0.f, 0.f};
#pragma unroll
    for (int ks = 0; ks < 8; ++ks) {
        const int ra = wid * 16 + fr;
        const bf16x8 a = *(const bf16x8*)(lQ + ra * 256 + (((ks * 4 + sl) ^ (ra & 7)) << 3));
#pragma unroll
        for (int ni = 0; ni < 4; ++ni) {
            const int rb = ni * 16 + fr;
            const bf16x8 bb = *(const bf16x8*)(lK + rb * 256 + (((ks * 4 + sl) ^ (rb & 7)) << 3));
            acc[ni] = __builtin_amdgcn_mfma_f32_16x16x32_bf16(a, bb, acc[ni], 0, 0, 0);
        }
    }
    float* gp = g2p + (long)blk * 4096;
#pragma unroll
    for (int ni = 0; ni < 4; ++ni)
#pragma unroll
        for (int rr = 0; rr < 4; ++rr)
            gp[(wid * 16 + sl * 4 + rr) * 64 + ni * 16 + fr] = acc[ni][rr];
}

// ---------------- fused: reduce gram partials + softmax + wmix -------------------
// grid: bh*4 + nseg (512). Softmax computed redundantly per nseg (cheap), written
// transposed into lA, then attn-fold into w_proj (k_wmix body).
__global__ __launch_bounds__(256) void k_swmix(
    const float* __restrict__ g2p, const float* __restrict__ sq2p,
    const float* __restrict__ temperature,
    const u16* __restrict__ wpT, u16* __restrict__ wmix)
{
    __shared__ u16 lA[64 * 72];
    __shared__ u16 lB[256 * 64];

    const int blk = blockIdx.x;
    const int nseg = blk & 3, bh = blk >> 2;
    const int b = bh >> 4, h = bh & 15;
    const int tid = threadIdx.x;
    const int wid = tid >> 6, lane = tid & 63;
    const int fr = lane & 15, sl = lane >> 4;

    // stage wpT panel
#pragma unroll
    for (int i = 0; i < 8; ++i) {
        const int cc = wid * 8 + i;
        const int row = cc * 8 + (lane >> 3);
        const int slot = lane & 7;
        const u16* g = wpT + (long)(nseg * 256 + row) * 1024 + h * 64 + ((slot ^ (row & 7)) << 3);
        __builtin_amdgcn_global_load_lds((gp_t)g, (lp_t)(lB + cc * 512), 16, 0, 0);
    }

    // softmax: wave wid handles d = wid*16+i, lane = e; write transposed lA[e][d]
    {
        const int e = lane;
        const float* sp = sq2p + (long)bh * 512;
        float sqk = 0.f;
#pragma unroll
        for (int s = 0; s < 4; ++s) sqk += sp[s * 128 + 64 + e];
        const float rk = 1.f / fmaxf(sqrtf(sqk), 1e-12f);
        const float temp = temperature[h];
        const float* gp = g2p + (long)bh * 16384;
#pragma unroll 2
        for (int i = 0; i < 16; ++i) {
            const int d = wid * 16 + i;
            float raw = 0.f, sqq = 0.f;
#pragma unroll
            for (int s = 0; s < 4; ++s) {
                raw += gp[s * 4096 + d * 64 + e];
                sqq += sp[s * 128 + d];
            }
            const float rq = 1.f / fmaxf(sqrtf(sqq), 1e-12f);
            const float v = raw * rq * rk * temp;
            float mx = v;
#pragma unroll
            for (int o = 32; o; o >>= 1) mx = fmaxf(mx, __shfl_xor(mx, o));
            const float p = __expf(v - mx);
            float sum = p;
#pragma unroll
            for (int o = 32; o; o >>= 1) sum += __shfl_xor(sum, o);
            lA[e * 72 + d] = f2bf(p / sum);
        }
    }
    __syncthreads();

    f32x4 acc[4][4];
#pragma unroll
    for (int i = 0; i < 4; ++i)
#pragma unroll
        for (int j = 0; j < 4; ++j) acc[i][j] = (f32x4){0.f, 0.f, 0.f, 0.f};

#pragma unroll
    for (int ks = 0; ks < 2; ++ks) {
        bf16x8 a[4], bb[4];
#pragma unroll
        for (int mi = 0; mi < 4; ++mi)
            a[mi] = *(const bf16x8*)(lA + (mi * 16 + fr) * 72 + ks * 32 + sl * 8);
#pragma unroll
        for (int ni = 0; ni < 4; ++ni) {
            const int rb = wid * 64 + ni * 16 + fr;
            bb[ni] = *(const bf16x8*)(lB + rb * 64 + (((ks * 4 + sl) ^ (rb & 7)) << 3));
        }
#pragma unroll
        for (int mi = 0; mi < 4; ++mi)
#pragma unroll
            for (int ni = 0; ni < 4; ++ni)
                acc[mi][ni] = __builtin_amdgcn_mfma_f32_16x16x32_bf16(a[mi], bb[ni], acc[mi][ni], 0, 0, 0);
    }

    u16* dst = wmix + ((long)b << 20);
#pragma unroll
    for (int mi = 0; mi < 4; ++mi)
#pragma unroll
        for (int ni = 0; ni < 4; ++ni) {
            const int cout = nseg * 256 + wid * 64 + ni * 16 + fr;
            const int e0 = mi * 16 + sl * 4;
            ushort4 w;
            w.x = f2bf(acc[mi][ni][0]); w.y = f2bf(acc[mi][ni][1]);
            w.z = f2bf(acc[mi][ni][2]); w.w = f2bf(acc[mi][ni][3]);
            *(ushort4*)(dst + (long)cout * 1024 + h * 64 + e0) = w;
        }
}

// ---------------- launch ----------------
extern "C" void kernel_launch(void* const* d_in, const int* in_sizes, int n_in,
                              void* d_out, int out_size, void* d_ws, size_t ws_size,
                              hipStream_t stream) {
    const float* x = (const float*)d_in[0];
    const float* w_qkv = (const float*)d_in[1];
    const float* temperature = (const float*)d_in[2];
    const float* w_proj = (const float*)d_in[3];
    const float* b_proj = (const float*)d_in[4];
    float* out = (float*)d_out;
    char* ws = (char*)d_ws;

    u16* wqT    = (u16*)(ws);                       //   6,291,456 B [3072][1024] bf16
    u16* wpT    = (u16*)(ws + 6291456);             //   2,097,152 B [1024][1024] bf16
    u16* wvb    = (u16*)(ws + 8388608);             //   2,097,152 B [1024][1024] bf16
    u16* xt     = (u16*)(ws + 10485760);            //  67,108,864 B [32768][1024] bf16
    u16* xc     = (u16*)(ws + 77594624);            //  67,108,864 B [8][1024][4096] bf16
    u16* S      = (u16*)(ws + 144703488);           //  16,777,216 B [8][1024][1024] bf16
    float* Sp   = (float*)(ws + 161480704);         //  75,497,472 B [1152][128][128] f32 (dead after k_sred)
    u16* Ut     = (u16*)(ws + 161480704);           //  33,554,432 B (overlays Sp after k_sred)
    float* g2p  = (float*)(ws + 195035136);         //   8,388,608 B [512][64][64] f32
    float* sq2p = (float*)(ws + 203423744);         //     262,144 B [512][128] f32
    u16* wmix   = (u16*)(ws + 204734464);           //  16,777,216 B
    u16* wfinT  = (u16*)(ws + 221511680);           //  16,777,216 B

    k_pack2<<<8192, 256, 0, stream>>>(x, xt, xc);
    k_prep<<<1536, 256, 0, stream>>>(w_qkv, w_proj, wqT, wpT, wvb);
    // S partials: 8 x 36 tri x 4 ksegs
    k_g128p<<<1152, 256, 0, stream>>>(xc, Sp);
    k_sred<<<288, 256, 0, stream>>>(Sp, S);
    // Ut_b = wqT(0..2048) @ S_b (S symmetric): 8 x 16 x 8 = 1024 blocks
    k_g128<<<1024, 256, 0, stream>>>(wqT, 0L, S, 1048576L, Ut, 2097152L, 1024, 16, 8);
    k_gram2p<<<512, 256, 0, stream>>>(wqT, Ut, g2p, sq2p);
    k_swmix<<<512, 256, 0, stream>>>(g2p, sq2p, temperature, wpT, wmix);
    // wfinT_b[cout][cin] = sum_e wmix_b[cout][e] * wvb[cin][e]
    k_g128<<<512, 256, 0, stream>>>(wmix, 1048576L, wvb, 0L, wfinT, 1048576L, 1024, 8, 8);
    // out = xt @ wfinT_b^T + bias: 8 x 32 x 8 = 2048 blocks
    k_g128f<<<2048, 256, 0, stream>>>(xt, 4194304L, wfinT, 1048576L, out, 4194304L, 1024, 32, 8, b_proj);
}

// Round 14
// 345.267 us; speedup vs baseline: 1.1838x; 1.1838x over previous
//
#include <hip/hip_runtime.h>
#include <cstdint>

typedef unsigned short u16;
typedef unsigned int u32;
typedef __attribute__((ext_vector_type(8))) short bf16x8;
typedef __attribute__((ext_vector_type(4))) float f32x4;

typedef const u32 __attribute__((address_space(1)))* gp_t;
typedef u32 __attribute__((address_space(3)))* lp_t;

__device__ __forceinline__ u16 f2bf(float f) {
    union { float f; u32 u; } v; v.f = f;
    u32 r = v.u + 0x7FFFu + ((v.u >> 16) & 1u);   // RNE
    return (u16)(r >> 16);
}
__device__ __forceinline__ float bf2f(u16 h) {
    union { u32 u; float f; } v; v.u = ((u32)h) << 16;
    return v.f;
}

// ---------------- pack x -> xt (token-major bf16) + xc (channel-major bf16) ----
__global__ __launch_bounds__(256) void k_pack2(const float* __restrict__ x,
                                               u16* __restrict__ xt, u16* __restrict__ xc) {
    __shared__ u16 tb[64][72];
    const int blk = blockIdx.x;
    const int tt = blk >> 4, ct = blk & 15;
    const long tok0 = (long)tt * 64;
    const int ch0 = ct * 64;
    const int tid = threadIdx.x;
    const int row = tid >> 2, cq = tid & 3;
#pragma unroll
    for (int jj = 0; jj < 4; ++jj) {
        const float4 v = *(const float4*)(x + (tok0 + row) * 1024 + ch0 + cq * 16 + jj * 4);
        tb[row][cq * 16 + jj * 4 + 0] = f2bf(v.x);
        tb[row][cq * 16 + jj * 4 + 1] = f2bf(v.y);
        tb[row][cq * 16 + jj * 4 + 2] = f2bf(v.z);
        tb[row][cq * 16 + jj * 4 + 3] = f2bf(v.w);
    }
    __syncthreads();
#pragma unroll
    for (int s = 0; s < 2; ++s) {
        const int c = s * 256 + tid;
        const int r2 = c >> 3, col8 = c & 7;
        *(uint4*)(xt + (tok0 + r2) * 1024 + ch0 + col8 * 8) = *(const uint4*)(&tb[r2][col8 * 8]);
    }
    const int b = (int)(tok0 >> 12);
    const int nin = (int)(tok0 & 4095);
#pragma unroll
    for (int s = 0; s < 2; ++s) {
        const int c = s * 256 + tid;
        const int crow = c >> 3, t8 = c & 7;
        u16 u[8];
#pragma unroll
        for (int k = 0; k < 8; ++k) u[k] = tb[t8 * 8 + k][crow];
        *(uint4*)(xc + ((long)b * 1024 + ch0 + crow) * 4096 + nin + t8 * 8) = *(const uint4*)u;
    }
}

// ---------------- fused prep: wqT transpose / wpT transpose / wvb pack ----------
__global__ __launch_bounds__(256) void k_prep(
    const float* __restrict__ wqkv, const float* __restrict__ wproj,
    u16* __restrict__ wqT, u16* __restrict__ wpT, u16* __restrict__ wvb)
{
    __shared__ float t[64][65];
    const int blk = blockIdx.x;
    const int tid = threadIdx.x;
    if (blk < 1024) {
        const float* src; u16* dst; int ncols, lb;
        if (blk < 768) { src = wqkv; dst = wqT; ncols = 3072; lb = blk; }
        else           { src = wproj; dst = wpT; ncols = 1024; lb = blk - 768; }
        const int ntn = ncols >> 6;
        const int kb = (lb / ntn) * 64;
        const int nb = (lb % ntn) * 64;
        for (int i = tid; i < 4096; i += 256) {
            int r = i >> 6, c = i & 63;
            t[r][c] = src[(long)(kb + r) * ncols + nb + c];
        }
        __syncthreads();
        for (int i = tid; i < 4096; i += 256) {
            int r = i >> 6, c = i & 63;
            dst[(long)(nb + r) * 1024 + kb + c] = f2bf(t[c][r]);
        }
    } else {
        const int idx = (blk - 1024) * 256 + tid;   // [0, 131072)
        const int cin = idx >> 7, e0 = (idx & 127) * 8;
        const float4 v1 = *(const float4*)(wqkv + (long)cin * 3072 + 2048 + e0);
        const float4 v2 = *(const float4*)(wqkv + (long)cin * 3072 + 2048 + e0 + 4);
        u16 u[8];
        u[0] = f2bf(v1.x); u[1] = f2bf(v1.y); u[2] = f2bf(v1.z); u[3] = f2bf(v1.w);
        u[4] = f2bf(v2.x); u[5] = f2bf(v2.y); u[6] = f2bf(v2.z); u[7] = f2bf(v2.w);
        *(uint4*)(wvb + (long)cin * 1024 + e0) = *(const uint4*)u;
    }
}

// ---------------- S partials: 128x128 tile x K=1024 segment of xc_b @ xc_b^T -----
__global__ __launch_bounds__(256) void k_g128p(
    const u16* __restrict__ xc, float* __restrict__ Sp)
{
    __shared__ u16 sm[8192];

    const int tid = threadIdx.x;
    const int wid = tid >> 6, lane = tid & 63;
    const int wr = wid >> 1, wc = wid & 1;
    const int fr = lane & 15, sl = lane >> 4;

    const int nwg = gridDim.x;
    const int logical = (blockIdx.x & 7) * (nwg >> 3) + (blockIdx.x >> 3);
    const int kseg = logical & 3;
    const int bt = logical >> 2;
    const int b = bt / 36;
    int t = bt % 36;
    int i0 = 0;
    while (t >= 8 - i0) { t -= 8 - i0; ++i0; }
    const int j0 = i0 + t;
    const int m0 = i0 * 128, n0 = j0 * 128;

    const u16* base = xc + (long)b * 4194304 + kseg * 1024;

    const int srow = lane >> 2;
    const int sslot = lane & 3;

    f32x4 acc[4][4];
#pragma unroll
    for (int i = 0; i < 4; ++i)
#pragma unroll
        for (int j = 0; j < 4; ++j) acc[i][j] = (f32x4){0.f, 0.f, 0.f, 0.f};

    for (int kt = 0; kt < 1024; kt += 32) {
        __syncthreads();
#pragma unroll
        for (int i = 0; i < 2; ++i) {
            const int row = wid * 32 + i * 16 + srow;
            const int swz = (sslot ^ ((row >> 1) & 3)) << 3;
            const u16* ga = base + (long)(m0 + row) * 4096 + kt + swz;
            const u16* gb = base + (long)(n0 + row) * 4096 + kt + swz;
            __builtin_amdgcn_global_load_lds((gp_t)ga, (lp_t)(sm + (wid * 2 + i) * 512), 16, 0, 0);
            __builtin_amdgcn_global_load_lds((gp_t)gb, (lp_t)(sm + 4096 + (wid * 2 + i) * 512), 16, 0, 0);
        }
        __syncthreads();
        bf16x8 af[4], bfr[4];
#pragma unroll
        for (int mi = 0; mi < 4; ++mi) {
            const int row = wr * 64 + mi * 16 + fr;
            af[mi] = *(const bf16x8*)(sm + row * 32 + ((sl ^ ((row >> 1) & 3)) << 3));
        }
#pragma unroll
        for (int ni = 0; ni < 4; ++ni) {
            const int row = wc * 64 + ni * 16 + fr;
            bfr[ni] = *(const bf16x8*)(sm + 4096 + row * 32 + ((sl ^ ((row >> 1) & 3)) << 3));
        }
#pragma unroll
        for (int mi = 0; mi < 4; ++mi)
#pragma unroll
            for (int ni = 0; ni < 4; ++ni)
                acc[mi][ni] = __builtin_amdgcn_mfma_f32_16x16x32_bf16(af[mi], bfr[ni], acc[mi][ni], 0, 0, 0);
    }

    float* gp = Sp + (long)logical * 16384;
#pragma unroll
    for (int mi = 0; mi < 4; ++mi)
#pragma unroll
        for (int ni = 0; ni < 4; ++ni)
#pragma unroll
            for (int rr = 0; rr < 4; ++rr)
                gp[(wr * 64 + mi * 16 + sl * 4 + rr) * 128 + wc * 64 + ni * 16 + fr] = acc[mi][ni][rr];
}

// ---------------- reduce 4 S partials -> bf16 S, row-major + transposed ----------
__global__ __launch_bounds__(256) void k_sred(const float* __restrict__ Sp, u16* __restrict__ S)
{
    __shared__ u16 lC[128 * 136];
    __shared__ u16 lCT[128 * 136];

    const int tid = threadIdx.x;
    const int nwg = gridDim.x;               // 288
    const int logical = (blockIdx.x & 7) * (nwg >> 3) + (blockIdx.x >> 3);
    const int b = logical / 36;
    int t = logical % 36;
    int i0 = 0;
    while (t >= 8 - i0) { t -= 8 - i0; ++i0; }
    const int j0 = i0 + t;
    const int m0 = i0 * 128, n0 = j0 * 128;

    const float* p = Sp + (long)logical * 65536;
    for (int i = tid; i < 16384; i += 256) {
        const float s = p[i] + p[i + 16384] + p[i + 32768] + p[i + 49152];
        const u16 v = f2bf(s);
        const int r_ = i >> 7, c_ = i & 127;
        lC[r_ * 136 + c_] = v;
        lCT[c_ * 136 + r_] = v;
    }
    __syncthreads();
    const int tk = tid >> 1, half = tid & 1;
    {
        u16* dp = S + (long)b * 1048576 + (long)(m0 + tk) * 1024 + n0 + half * 64;
        const u16* sp1 = lC + tk * 136 + half * 64;
#pragma unroll
        for (int i = 0; i < 8; ++i) ((uint4*)dp)[i] = ((const uint4*)sp1)[i];
    }
    if (i0 != j0) {
        u16* dp = S + (long)b * 1048576 + (long)(n0 + tk) * 1024 + m0 + half * 64;
        const u16* sp2 = lCT + tk * 136 + half * 64;
#pragma unroll
        for (int i = 0; i < 8; ++i) ((uint4*)dp)[i] = ((const uint4*)sp2)[i];
    }
}

// ---------------- 128x128 GEMM, BK=32, batched, bf16 out (wfinT) -----------------
__global__ __launch_bounds__(256) void k_g128(
    const u16* __restrict__ A, long Ab, const u16* __restrict__ Bt, long Bs,
    u16* __restrict__ C, long Cb, int K, int MT, int NT)
{
    __shared__ u16 sm[8192];
    __shared__ u16 lC[128 * 136];

    const int tid = threadIdx.x;
    const int wid = tid >> 6, lane = tid & 63;
    const int wr = wid >> 1, wc = wid & 1;
    const int fr = lane & 15, sl = lane >> 4;

    const int nwg = gridDim.x;
    const int logical = (blockIdx.x & 7) * (nwg >> 3) + (blockIdx.x >> 3);

    const int b = logical / (MT * NT);
    const int r = logical % (MT * NT);
    const int i0 = r / NT, j0 = r % NT;
    const int m0 = i0 * 128, n0 = j0 * 128;
    const u16* Abp = A + (long)b * Ab;
    const u16* Bbp = Bt + (long)b * Bs;
    u16* Cbp = C + (long)b * Cb;

    const int srow = lane >> 2;
    const int sslot = lane & 3;

    f32x4 acc[4][4];
#pragma unroll
    for (int i = 0; i < 4; ++i)
#pragma unroll
        for (int j = 0; j < 4; ++j) acc[i][j] = (f32x4){0.f, 0.f, 0.f, 0.f};

    for (int kt = 0; kt < K; kt += 32) {
        __syncthreads();
#pragma unroll
        for (int i = 0; i < 2; ++i) {
            const int row = wid * 32 + i * 16 + srow;
            const int swz = (sslot ^ ((row >> 1) & 3)) << 3;
            const u16* ga = Abp + (long)(m0 + row) * K + kt + swz;
            const u16* gb = Bbp + (long)(n0 + row) * K + kt + swz;
            __builtin_amdgcn_global_load_lds((gp_t)ga, (lp_t)(sm + (wid * 2 + i) * 512), 16, 0, 0);
            __builtin_amdgcn_global_load_lds((gp_t)gb, (lp_t)(sm + 4096 + (wid * 2 + i) * 512), 16, 0, 0);
        }
        __syncthreads();
        bf16x8 af[4], bfr[4];
#pragma unroll
        for (int mi = 0; mi < 4; ++mi) {
            const int row = wr * 64 + mi * 16 + fr;
            af[mi] = *(const bf16x8*)(sm + row * 32 + ((sl ^ ((row >> 1) & 3)) << 3));
        }
#pragma unroll
        for (int ni = 0; ni < 4; ++ni) {
            const int row = wc * 64 + ni * 16 + fr;
            bfr[ni] = *(const bf16x8*)(sm + 4096 + row * 32 + ((sl ^ ((row >> 1) & 3)) << 3));
        }
#pragma unroll
        for (int mi = 0; mi < 4; ++mi)
#pragma unroll
            for (int ni = 0; ni < 4; ++ni)
                acc[mi][ni] = __builtin_amdgcn_mfma_f32_16x16x32_bf16(af[mi], bfr[ni], acc[mi][ni], 0, 0, 0);
    }
    __syncthreads();

#pragma unroll
    for (int mi = 0; mi < 4; ++mi)
#pragma unroll
        for (int ni = 0; ni < 4; ++ni) {
            const int ch = wc * 64 + ni * 16 + fr;
            const int tk = wr * 64 + mi * 16 + sl * 4;
#pragma unroll
            for (int rr = 0; rr < 4; ++rr)
                lC[(tk + rr) * 136 + ch] = f2bf(acc[mi][ni][rr]);
        }
    __syncthreads();
    {
        const int tk = tid >> 1, half = tid & 1;
        const u16* sp = lC + tk * 136 + half * 64;
        u16* dp = Cbp + (long)(m0 + tk) * 1024 + n0 + half * 64;
#pragma unroll
        for (int i = 0; i < 8; ++i) ((uint4*)dp)[i] = ((const uint4*)sp)[i];
    }
}

// ---------------- 256x256 GEMM, BK=64, K=1024, batched; EPI 0=bf16, 1=f32+bias ---
template<int EPI>
__global__ __launch_bounds__(512, 2) void k_gemm256(
    const u16* __restrict__ A, long Ab, const u16* __restrict__ Bt, long Bs,
    int MT, int NT,
    u16* __restrict__ cB, float* __restrict__ cF, long Cb, const float* __restrict__ bias)
{
    __shared__ uint4 smem4[8704];
    u16* sm = (u16*)smem4;

    const int tid = threadIdx.x;
    const int wid = tid >> 6, lane = tid & 63;
    const int wr = wid >> 2, wc = wid & 3;
    const int fr = lane & 15, sl = lane >> 4;

    const int nwg = gridDim.x;
    const int logical = (blockIdx.x & 7) * (nwg >> 3) + (blockIdx.x >> 3);
    const int b = logical / (MT * NT);
    const int rem = logical % (MT * NT);
    const int mt = rem / NT, nt = rem % NT;
    const long m0 = (long)mt * 256;
    const int n0 = nt * 256;

    const int srow = wid * 32 + (lane >> 2);
    const int kswz = (((lane & 3) ^ ((srow >> 1) & 3)) << 3);
    const u16* gA = A + (long)b * Ab + (m0 + srow) * 1024L + kswz;
    const u16* gB = Bt + (long)b * Bs + ((long)n0 + srow) * 1024L + kswz;
    const int ldst = wid * 1024;

    const int fxor = ((sl ^ ((fr >> 1) & 3)) << 3);
    const int aBase = (wr * 128 + fr) * 32 + fxor;
    const int bBase = 32768 + (wc * 64 + fr) * 32 + fxor;

    f32x4 acc[8][4];
#pragma unroll
    for (int i = 0; i < 8; ++i)
#pragma unroll
        for (int j = 0; j < 4; ++j) acc[i][j] = (f32x4){0.f, 0.f, 0.f, 0.f};

#define STAGE_A(d, kh, ts) do { \
    const u16* g_ = gA + (ts) * 64 + (kh) * 32; \
    u16* l_ = sm + (d) * 16384 + (kh) * 8192 + ldst; \
    __builtin_amdgcn_global_load_lds((gp_t)g_, (lp_t)l_, 16, 0, 0); \
    __builtin_amdgcn_global_load_lds((gp_t)(g_ + 16 * 1024), (lp_t)(l_ + 512), 16, 0, 0); \
} while (0)
#define STAGE_B(d, kh, ts) do { \
    const u16* g_ = gB + (ts) * 64 + (kh) * 32; \
    u16* l_ = sm + 32768 + (d) * 16384 + (kh) * 8192 + ldst; \
    __builtin_amdgcn_global_load_lds((gp_t)g_, (lp_t)l_, 16, 0, 0); \
    __builtin_amdgcn_global_load_lds((gp_t)(g_ + 16 * 1024), (lp_t)(l_ + 512), 16, 0, 0); \
} while (0)

    STAGE_A(0, 0, 0); STAGE_B(0, 0, 0);
    STAGE_A(0, 1, 0); STAGE_B(0, 1, 0);
    STAGE_A(1, 0, 1); STAGE_B(1, 0, 1);
    asm volatile("s_waitcnt vmcnt(8)" ::: "memory");
    __builtin_amdgcn_s_barrier();

    bf16x8 afX[4], afY[4], bfX[4], bfY[4];
#pragma unroll
    for (int ni = 0; ni < 4; ++ni) bfX[ni] = *(const bf16x8*)(sm + bBase + ni * 512);
#pragma unroll
    for (int mi = 0; mi < 4; ++mi) afX[mi] = *(const bf16x8*)(sm + aBase + mi * 512);

#pragma unroll 2
    for (int T = 0; T < 16; ++T) {
        const int d = T & 1;
        const int t1 = (T + 1 < 16) ? T + 1 : 15;
        const int t2 = (T + 2 < 16) ? T + 2 : 15;
        const int base = d * 16384;
        const int nbase = (d ^ 1) * 16384;

#pragma unroll
        for (int mi = 0; mi < 4; ++mi)
            afY[mi] = *(const bf16x8*)(sm + aBase + (4 + mi) * 512 + base);
        STAGE_A(d ^ 1, 1, t1);
        asm volatile("s_waitcnt vmcnt(6)" ::: "memory");
        __builtin_amdgcn_s_barrier();
        __builtin_amdgcn_s_setprio(1);
#pragma unroll
        for (int mi = 0; mi < 4; ++mi)
#pragma unroll
            for (int ni = 0; ni < 4; ++ni)
                acc[mi][ni] = __builtin_amdgcn_mfma_f32_16x16x32_bf16(afX[mi], bfX[ni], acc[mi][ni], 0, 0, 0);
        __builtin_amdgcn_s_setprio(0);
        __builtin_amdgcn_s_barrier();

#pragma unroll
        for (int ni = 0; ni < 4; ++ni)
            bfY[ni] = *(const bf16x8*)(sm + bBase + ni * 512 + base + 8192);
#pragma unroll
        for (int mi = 0; mi < 4; ++mi)
            afX[mi] = *(const bf16x8*)(sm + aBase + mi * 512 + base + 8192);
        STAGE_B(d ^ 1, 1, t1);
        __builtin_amdgcn_s_barrier();
        __builtin_amdgcn_s_setprio(1);
#pragma unroll
        for (int mi = 0; mi < 4; ++mi)
#pragma unroll
            for (int ni = 0; ni < 4; ++ni)
                acc[mi + 4][ni] = __builtin_amdgcn_mfma_f32_16x16x32_bf16(afY[mi], bfX[ni], acc[mi + 4][ni], 0, 0, 0);
        __builtin_amdgcn_s_setprio(0);
        __builtin_amdgcn_s_barrier();

#pragma unroll
        for (int mi = 0; mi < 4; ++mi)
            afY[mi] = *(const bf16x8*)(sm + aBase + (4 + mi) * 512 + base + 8192);
        STAGE_A(d, 0, t2);
        asm volatile("s_waitcnt vmcnt(6)" ::: "memory");
        __builtin_amdgcn_s_barrier();
        __builtin_amdgcn_s_setprio(1);
#pragma unroll
        for (int mi = 0; mi < 4; ++mi)
#pragma unroll
            for (int ni = 0; ni < 4; ++ni)
                acc[mi][ni] = __builtin_amdgcn_mfma_f32_16x16x32_bf16(afX[mi], bfY[ni], acc[mi][ni], 0, 0, 0);
        __builtin_amdgcn_s_setprio(0);
        __builtin_amdgcn_s_barrier();

#pragma unroll
        for (int ni = 0; ni < 4; ++ni)
            bfX[ni] = *(const bf16x8*)(sm + bBase + ni * 512 + nbase);
#pragma unroll
        for (int mi = 0; mi < 4; ++mi)
            afX[mi] = *(const bf16x8*)(sm + aBase + mi * 512 + nbase);
        STAGE_B(d, 0, t2);
        __builtin_amdgcn_s_barrier();
        __builtin_amdgcn_s_setprio(1);
#pragma unroll
        for (int mi = 0; mi < 4; ++mi)
#pragma unroll
            for (int ni = 0; ni < 4; ++ni)
                acc[mi + 4][ni] = __builtin_amdgcn_mfma_f32_16x16x32_bf16(afY[mi], bfY[ni], acc[mi + 4][ni], 0, 0, 0);
        __builtin_amdgcn_s_setprio(0);
        __builtin_amdgcn_s_barrier();
    }
#undef STAGE_A
#undef STAGE_B
    asm volatile("s_waitcnt vmcnt(0)" ::: "memory");
    __syncthreads();

    if (EPI == 0) {
        u16* cbase = cB + (long)b * Cb;
        u16* piece = sm + wid * 8704;
#pragma unroll
        for (int mi = 0; mi < 8; ++mi)
#pragma unroll
            for (int ni = 0; ni < 4; ++ni) {
                const int ch = ni * 16 + fr;
                const int tk = mi * 16 + sl * 4;
#pragma unroll
                for (int rr = 0; rr < 4; ++rr)
                    piece[(tk + rr) * 68 + ch] = f2bf(acc[mi][ni][rr]);
            }
        __syncthreads();
#pragma unroll
        for (int i = 0; i < 32; ++i) {
            const int chunk = i * 512 + tid;
            const int row = chunk >> 4, c8 = chunk & 15;
            const int p = row >> 7, tk = row & 127;
            const int wrp = p >> 2, wcp = p & 3;
            const uint2 v = *(const uint2*)(sm + p * 8704 + tk * 68 + c8 * 4);
            *(uint2*)(cbase + (m0 + wrp * 128 + tk) * 1024L + n0 + wcp * 64 + c8 * 4) = v;
        }
    } else {
        float* cbase = cF + (long)b * Cb;
        float bi[4];
#pragma unroll
        for (int ni = 0; ni < 4; ++ni) bi[ni] = bias[n0 + wc * 64 + ni * 16 + fr];
#pragma unroll
        for (int pass = 0; pass < 2; ++pass) {
            float* pieceF = (float*)smem4 + wid * 4352;
            if (pass) __syncthreads();
#pragma unroll
            for (int mi2 = 0; mi2 < 4; ++mi2) {
                const int mi = pass * 4 + mi2;
#pragma unroll
                for (int ni = 0; ni < 4; ++ni) {
                    const int ch = ni * 16 + fr;
                    const int tk = mi2 * 16 + sl * 4;
#pragma unroll
                    for (int rr = 0; rr < 4; ++rr)
                        pieceF[(tk + rr) * 68 + ch] = acc[mi][ni][rr] + bi[ni];
                }
            }
            __syncthreads();
#pragma unroll
            for (int i = 0; i < 16; ++i) {
                const int chunk = i * 512 + tid;
                const int row = chunk >> 4, c4 = chunk & 15;
                const int p = row >> 6, tk = row & 63;
                const int wrp = p >> 2, wcp = p & 3;
                const float4 v = *(const float4*)((float*)smem4 + p * 4352 + tk * 68 + c4 * 4);
                *(float4*)(cbase + (m0 + wrp * 128 + pass * 64 + tk) * 1024L + n0 + wcp * 64 + c4 * 4) = v;
            }
        }
    }
}

// ---------------- gram partials per (b,h,kseg): 64x64 Gram + 128 row-dots --------
__global__ __launch_bounds__(256) void k_gram2p(
    const u16* __restrict__ wqT, const u16* __restrict__ Ut,
    float* __restrict__ g2p, float* __restrict__ sq2p)
{
    __shared__ u16 lQ[64 * 256];
    __shared__ u16 lK[64 * 256];

    const int blk = blockIdx.x;           // bh*4 + seg
    const int seg = blk & 3, bh = blk >> 2;
    const int b = bh >> 4, h = bh & 15;
    const int tid = threadIdx.x;
    const int wid = tid >> 6, lane = tid & 63;

    {
        const int r2 = lane >> 5, slot = lane & 31;
        const int rbase = wid * 16;
#pragma unroll
        for (int i = 0; i < 8; ++i) {
            const int r = rbase + i * 2 + r2;
            const int col = seg * 256 + ((slot ^ (r & 7)) << 3);
            const u16* gq = wqT + (long)(h * 64 + r) * 1024 + col;
            const u16* gk = Ut + ((long)b * 2048 + 1024 + h * 64 + r) * 1024 + col;
            __builtin_amdgcn_global_load_lds((gp_t)gq, (lp_t)(lQ + (rbase + i * 2) * 256), 16, 0, 0);
            __builtin_amdgcn_global_load_lds((gp_t)gk, (lp_t)(lK + (rbase + i * 2) * 256), 16, 0, 0);
        }
    }
    __syncthreads();

    {
        const int row = tid >> 1, half = tid & 1;
        const int j = (row < 64) ? (h * 64 + row) : (1024 + h * 64 + (row - 64));
        const u16* pa = wqT + (long)j * 1024 + seg * 256 + half * 128;
        const u16* pb = Ut + ((long)b * 2048 + j) * 1024 + seg * 256 + half * 128;
        float s = 0.f;
#pragma unroll 4
        for (int i = 0; i < 16; ++i) {
            const uint4 a = *(const uint4*)(pa + i * 8);
            const uint4 bv = *(const uint4*)(pb + i * 8);
            s += bf2f((u16)(a.x & 0xFFFF)) * bf2f((u16)(bv.x & 0xFFFF));
            s += bf2f((u16)(a.x >> 16))    * bf2f((u16)(bv.x >> 16));
            s += bf2f((u16)(a.y & 0xFFFF)) * bf2f((u16)(bv.y & 0xFFFF));
            s += bf2f((u16)(a.y >> 16))    * bf2f((u16)(bv.y >> 16));
            s += bf2f((u16)(a.z & 0xFFFF)) * bf2f((u16)(bv.z & 0xFFFF));
            s += bf2f((u16)(a.z >> 16))    * bf2f((u16)(bv.z >> 16));
            s += bf2f((u16)(a.w & 0xFFFF)) * bf2f((u16)(bv.w & 0xFFFF));
            s += bf2f((u16)(a.w >> 16))    * bf2f((u16)(bv.w >> 16));
        }
        s += __shfl_xor(s, 1);
        if (half == 0) sq2p[(long)blk * 128 + row] = s;
    }

    const int fr = lane & 15, sl = lane >> 4;
    f32x4 acc[4];
#pragma unroll
    for (int i = 0; i < 4; ++i) acc[i] = (f32x4){0.f, 0.f, 0.f, 0.f};
#pragma unroll
    for (int ks = 0; ks < 8; ++ks) {
        const int ra = wid * 16 + fr;
        const bf16x8 a = *(const bf16x8*)(lQ + ra * 256 + (((ks * 4 + sl) ^ (ra & 7)) << 3));
#pragma unroll
        for (int ni = 0; ni < 4; ++ni) {
            const int rb = ni * 16 + fr;
            const bf16x8 bb = *(const bf16x8*)(lK + rb * 256 + (((ks * 4 + sl) ^ (rb & 7)) << 3));
            acc[ni] = __builtin_amdgcn_mfma_f32_16x16x32_bf16(a, bb, acc[ni], 0, 0, 0);
        }
    }
    float* gp = g2p + (long)blk * 4096;
#pragma unroll
    for (int ni = 0; ni < 4; ++ni)
#pragma unroll
        for (int rr = 0; rr < 4; ++rr)
            gp[(wid * 16 + sl * 4 + rr) * 64 + ni * 16 + fr] = acc[ni][rr];
}

// ---------------- fused: reduce gram partials + softmax + wmix -------------------
__global__ __launch_bounds__(256) void k_swmix(
    const float* __restrict__ g2p, const float* __restrict__ sq2p,
    const float* __restrict__ temperature,
    const u16* __restrict__ wpT, u16* __restrict__ wmix)
{
    __shared__ u16 lA[64 * 72];
    __shared__ u16 lB[256 * 64];

    const int blk = blockIdx.x;
    const int nseg = blk & 3, bh = blk >> 2;
    const int b = bh >> 4, h = bh & 15;
    const int tid = threadIdx.x;
    const int wid = tid >> 6, lane = tid & 63;
    const int fr = lane & 15, sl = lane >> 4;

#pragma unroll
    for (int i = 0; i < 8; ++i) {
        const int cc = wid * 8 + i;
        const int row = cc * 8 + (lane >> 3);
        const int slot = lane & 7;
        const u16* g = wpT + (long)(nseg * 256 + row) * 1024 + h * 64 + ((slot ^ (row & 7)) << 3);
        __builtin_amdgcn_global_load_lds((gp_t)g, (lp_t)(lB + cc * 512), 16, 0, 0);
    }

    {
        const int e = lane;
        const float* sp = sq2p + (long)bh * 512;
        float sqk = 0.f;
#pragma unroll
        for (int s = 0; s < 4; ++s) sqk += sp[s * 128 + 64 + e];
        const float rk = 1.f / fmaxf(sqrtf(sqk), 1e-12f);
        const float temp = temperature[h];
        const float* gp = g2p + (long)bh * 16384;
#pragma unroll 2
        for (int i = 0; i < 16; ++i) {
            const int d = wid * 16 + i;
            float raw = 0.f, sqq = 0.f;
#pragma unroll
            for (int s = 0; s < 4; ++s) {
                raw += gp[s * 4096 + d * 64 + e];
                sqq += sp[s * 128 + d];
            }
            const float rq = 1.f / fmaxf(sqrtf(sqq), 1e-12f);
            const float v = raw * rq * rk * temp;
            float mx = v;
#pragma unroll
            for (int o = 32; o; o >>= 1) mx = fmaxf(mx, __shfl_xor(mx, o));
            const float p = __expf(v - mx);
            float sum = p;
#pragma unroll
            for (int o = 32; o; o >>= 1) sum += __shfl_xor(sum, o);
            lA[e * 72 + d] = f2bf(p / sum);
        }
    }
    __syncthreads();

    f32x4 acc[4][4];
#pragma unroll
    for (int i = 0; i < 4; ++i)
#pragma unroll
        for (int j = 0; j < 4; ++j) acc[i][j] = (f32x4){0.f, 0.f, 0.f, 0.f};

#pragma unroll
    for (int ks = 0; ks < 2; ++ks) {
        bf16x8 a[4], bb[4];
#pragma unroll
        for (int mi = 0; mi < 4; ++mi)
            a[mi] = *(const bf16x8*)(lA + (mi * 16 + fr) * 72 + ks * 32 + sl * 8);
#pragma unroll
        for (int ni = 0; ni < 4; ++ni) {
            const int rb = wid * 64 + ni * 16 + fr;
            bb[ni] = *(const bf16x8*)(lB + rb * 64 + (((ks * 4 + sl) ^ (rb & 7)) << 3));
        }
#pragma unroll
        for (int mi = 0; mi < 4; ++mi)
#pragma unroll
            for (int ni = 0; ni < 4; ++ni)
                acc[mi][ni] = __builtin_amdgcn_mfma_f32_16x16x32_bf16(a[mi], bb[ni], acc[mi][ni], 0, 0, 0);
    }

    u16* dst = wmix + ((long)b << 20);
#pragma unroll
    for (int mi = 0; mi < 4; ++mi)
#pragma unroll
        for (int ni = 0; ni < 4; ++ni) {
            const int cout = nseg * 256 + wid * 64 + ni * 16 + fr;
            const int e0 = mi * 16 + sl * 4;
            ushort4 w;
            w.x = f2bf(acc[mi][ni][0]); w.y = f2bf(acc[mi][ni][1]);
            w.z = f2bf(acc[mi][ni][2]); w.w = f2bf(acc[mi][ni][3]);
            *(ushort4*)(dst + (long)cout * 1024 + h * 64 + e0) = w;
        }
}

// ---------------- launch ----------------
extern "C" void kernel_launch(void* const* d_in, const int* in_sizes, int n_in,
                              void* d_out, int out_size, void* d_ws, size_t ws_size,
                              hipStream_t stream) {
    const float* x = (const float*)d_in[0];
    const float* w_qkv = (const float*)d_in[1];
    const float* temperature = (const float*)d_in[2];
    const float* w_proj = (const float*)d_in[3];
    const float* b_proj = (const float*)d_in[4];
    float* out = (float*)d_out;
    char* ws = (char*)d_ws;

    u16* wqT    = (u16*)(ws);                       //   6,291,456 B [3072][1024] bf16
    u16* wpT    = (u16*)(ws + 6291456);             //   2,097,152 B [1024][1024] bf16
    u16* wvb    = (u16*)(ws + 8388608);             //   2,097,152 B [1024][1024] bf16
    u16* xt     = (u16*)(ws + 10485760);            //  67,108,864 B [32768][1024] bf16
    u16* xc     = (u16*)(ws + 77594624);            //  67,108,864 B [8][1024][4096] bf16
    u16* S      = (u16*)(ws + 144703488);           //  16,777,216 B [8][1024][1024] bf16
    float* Sp   = (float*)(ws + 161480704);         //  75,497,472 B [1152][128][128] f32 (dead after k_sred)
    u16* Ut     = (u16*)(ws + 161480704);           //  33,554,432 B (overlays Sp after k_sred)
    float* g2p  = (float*)(ws + 195035136);         //   8,388,608 B [512][64][64] f32
    float* sq2p = (float*)(ws + 203423744);         //     262,144 B [512][128] f32
    u16* wmix   = (u16*)(ws + 204734464);           //  16,777,216 B
    u16* wfinT  = (u16*)(ws + 221511680);           //  16,777,216 B

    k_pack2<<<8192, 256, 0, stream>>>(x, xt, xc);
    k_prep<<<1536, 256, 0, stream>>>(w_qkv, w_proj, wqT, wpT, wvb);
    // S partials: 8 x 36 tri x 4 ksegs
    k_g128p<<<1152, 256, 0, stream>>>(xc, Sp);
    k_sred<<<288, 256, 0, stream>>>(Sp, S);
    // Ut_b = wqT(0..2048) @ S_b (S symmetric): 8 x 8 x 4 = 256 blocks, 256^2 tiles
    k_gemm256<0><<<256, 512, 0, stream>>>(wqT, 0L, S, 1048576L, 8, 4, Ut, nullptr, 2097152L, nullptr);
    k_gram2p<<<512, 256, 0, stream>>>(wqT, Ut, g2p, sq2p);
    k_swmix<<<512, 256, 0, stream>>>(g2p, sq2p, temperature, wpT, wmix);
    // wfinT_b[cout][cin] = sum_e wmix_b[cout][e] * wvb[cin][e]
    k_g128<<<512, 256, 0, stream>>>(wmix, 1048576L, wvb, 0L, wfinT, 1048576L, 1024, 8, 8);
    // out = xt @ wfinT_b^T + bias: 8 x 16 x 4 = 512 blocks, 256^2 tiles
    k_gemm256<1><<<512, 512, 0, stream>>>(xt, 4194304L, wfinT, 1048576L, 16, 4, nullptr, out, 4194304L, b_proj);
}

// Round 15
// 317.027 us; speedup vs baseline: 1.2893x; 1.0891x over previous
//
#include <hip/hip_runtime.h>
#include <cstdint>

typedef unsigned short u16;
typedef unsigned int u32;
typedef __attribute__((ext_vector_type(8))) short bf16x8;
typedef __attribute__((ext_vector_type(4))) float f32x4;

typedef const u32 __attribute__((address_space(1)))* gp_t;
typedef u32 __attribute__((address_space(3)))* lp_t;

__device__ __forceinline__ u16 f2bf(float f) {
    union { float f; u32 u; } v; v.f = f;
    u32 r = v.u + 0x7FFFu + ((v.u >> 16) & 1u);   // RNE
    return (u16)(r >> 16);
}
__device__ __forceinline__ float bf2f(u16 h) {
    union { u32 u; float f; } v; v.u = ((u32)h) << 16;
    return v.f;
}

// ---------------- fused: pack x -> xt/xc  +  weight prep (wqT/wpT/wvb) ----------
// grid 9728: [0,8192) pack tiles, [8192,9216) transposes, [9216,9728) wvb pack
__global__ __launch_bounds__(256) void k_prepack(
    const float* __restrict__ x, const float* __restrict__ wqkv, const float* __restrict__ wproj,
    u16* __restrict__ xt, u16* __restrict__ xc,
    u16* __restrict__ wqT, u16* __restrict__ wpT, u16* __restrict__ wvb)
{
    __shared__ float tf[64][65];     // 16640 B (pack2 aliases as u16)
    const int blk = blockIdx.x;
    const int tid = threadIdx.x;

    if (blk < 8192) {
        u16* tb = (u16*)tf;          // [64][72] u16 view
        const int tt = blk >> 4, ct = blk & 15;
        const long tok0 = (long)tt * 64;
        const int ch0 = ct * 64;
        const int row = tid >> 2, cq = tid & 3;
#pragma unroll
        for (int jj = 0; jj < 4; ++jj) {
            const float4 v = *(const float4*)(x + (tok0 + row) * 1024 + ch0 + cq * 16 + jj * 4);
            tb[row * 72 + cq * 16 + jj * 4 + 0] = f2bf(v.x);
            tb[row * 72 + cq * 16 + jj * 4 + 1] = f2bf(v.y);
            tb[row * 72 + cq * 16 + jj * 4 + 2] = f2bf(v.z);
            tb[row * 72 + cq * 16 + jj * 4 + 3] = f2bf(v.w);
        }
        __syncthreads();
#pragma unroll
        for (int s = 0; s < 2; ++s) {
            const int c = s * 256 + tid;
            const int r2 = c >> 3, col8 = c & 7;
            *(uint4*)(xt + (tok0 + r2) * 1024 + ch0 + col8 * 8) = *(const uint4*)(&tb[r2 * 72 + col8 * 8]);
        }
        const int b = (int)(tok0 >> 12);
        const int nin = (int)(tok0 & 4095);
#pragma unroll
        for (int s = 0; s < 2; ++s) {
            const int c = s * 256 + tid;
            const int crow = c >> 3, t8 = c & 7;
            u16 u[8];
#pragma unroll
            for (int k = 0; k < 8; ++k) u[k] = tb[(t8 * 8 + k) * 72 + crow];
            *(uint4*)(xc + ((long)b * 1024 + ch0 + crow) * 4096 + nin + t8 * 8) = *(const uint4*)u;
        }
    } else if (blk < 9216) {
        const int lb0 = blk - 8192;
        const float* src; u16* dst; int ncols, lb;
        if (lb0 < 768) { src = wqkv; dst = wqT; ncols = 3072; lb = lb0; }
        else           { src = wproj; dst = wpT; ncols = 1024; lb = lb0 - 768; }
        const int ntn = ncols >> 6;
        const int kb = (lb / ntn) * 64;
        const int nb = (lb % ntn) * 64;
        for (int i = tid; i < 4096; i += 256) {
            int r = i >> 6, c = i & 63;
            tf[r][c] = src[(long)(kb + r) * ncols + nb + c];
        }
        __syncthreads();
        for (int i = tid; i < 4096; i += 256) {
            int r = i >> 6, c = i & 63;
            dst[(long)(nb + r) * 1024 + kb + c] = f2bf(tf[c][r]);
        }
    } else {
        const int idx = (blk - 9216) * 256 + tid;   // [0, 131072)
        const int cin = idx >> 7, e0 = (idx & 127) * 8;
        const float4 v1 = *(const float4*)(wqkv + (long)cin * 3072 + 2048 + e0);
        const float4 v2 = *(const float4*)(wqkv + (long)cin * 3072 + 2048 + e0 + 4);
        u16 u[8];
        u[0] = f2bf(v1.x); u[1] = f2bf(v1.y); u[2] = f2bf(v1.z); u[3] = f2bf(v1.w);
        u[4] = f2bf(v2.x); u[5] = f2bf(v2.y); u[6] = f2bf(v2.z); u[7] = f2bf(v2.w);
        *(uint4*)(wvb + (long)cin * 1024 + e0) = *(const uint4*)u;
    }
}

// ---------------- S partials: 128x128 tile x K=2048 segment, bf16 out ------------
// grid 576 = 8b x 36 tri-tiles x 2 ksegs.
__global__ __launch_bounds__(256) void k_g128p(
    const u16* __restrict__ xc, u16* __restrict__ Spb)
{
    __shared__ u16 sm[8192];

    const int tid = threadIdx.x;
    const int wid = tid >> 6, lane = tid & 63;
    const int wr = wid >> 1, wc = wid & 1;
    const int fr = lane & 15, sl = lane >> 4;

    const int nwg = gridDim.x;
    const int logical = (blockIdx.x & 7) * (nwg >> 3) + (blockIdx.x >> 3);
    const int kseg = logical & 1;
    const int bt = logical >> 1;
    const int b = bt / 36;
    int t = bt % 36;
    int i0 = 0;
    while (t >= 8 - i0) { t -= 8 - i0; ++i0; }
    const int j0 = i0 + t;
    const int m0 = i0 * 128, n0 = j0 * 128;

    const u16* base = xc + (long)b * 4194304 + kseg * 2048;

    const int srow = lane >> 2;
    const int sslot = lane & 3;

    f32x4 acc[4][4];
#pragma unroll
    for (int i = 0; i < 4; ++i)
#pragma unroll
        for (int j = 0; j < 4; ++j) acc[i][j] = (f32x4){0.f, 0.f, 0.f, 0.f};

    for (int kt = 0; kt < 2048; kt += 32) {
        __syncthreads();
#pragma unroll
        for (int i = 0; i < 2; ++i) {
            const int row = wid * 32 + i * 16 + srow;
            const int swz = (sslot ^ ((row >> 1) & 3)) << 3;
            const u16* ga = base + (long)(m0 + row) * 4096 + kt + swz;
            const u16* gb = base + (long)(n0 + row) * 4096 + kt + swz;
            __builtin_amdgcn_global_load_lds((gp_t)ga, (lp_t)(sm + (wid * 2 + i) * 512), 16, 0, 0);
            __builtin_amdgcn_global_load_lds((gp_t)gb, (lp_t)(sm + 4096 + (wid * 2 + i) * 512), 16, 0, 0);
        }
        __syncthreads();
        bf16x8 af[4], bfr[4];
#pragma unroll
        for (int mi = 0; mi < 4; ++mi) {
            const int row = wr * 64 + mi * 16 + fr;
            af[mi] = *(const bf16x8*)(sm + row * 32 + ((sl ^ ((row >> 1) & 3)) << 3));
        }
#pragma unroll
        for (int ni = 0; ni < 4; ++ni) {
            const int row = wc * 64 + ni * 16 + fr;
            bfr[ni] = *(const bf16x8*)(sm + 4096 + row * 32 + ((sl ^ ((row >> 1) & 3)) << 3));
        }
#pragma unroll
        for (int mi = 0; mi < 4; ++mi)
#pragma unroll
            for (int ni = 0; ni < 4; ++ni)
                acc[mi][ni] = __builtin_amdgcn_mfma_f32_16x16x32_bf16(af[mi], bfr[ni], acc[mi][ni], 0, 0, 0);
    }

    u16* gp = Spb + (long)logical * 16384;
#pragma unroll
    for (int mi = 0; mi < 4; ++mi)
#pragma unroll
        for (int ni = 0; ni < 4; ++ni) {
            const int rw = wr * 64 + mi * 16 + sl * 4;
            const int cl = wc * 64 + ni * 16 + fr;
#pragma unroll
            for (int rr = 0; rr < 4; ++rr)
                gp[(rw + rr) * 128 + cl] = f2bf(acc[mi][ni][rr]);
        }
}

// ---------------- reduce 2 bf16 S partials -> bf16 S, row-major + transposed -----
__global__ __launch_bounds__(256) void k_sred(const u16* __restrict__ Spb, u16* __restrict__ S)
{
    __shared__ u16 lC[128 * 136];
    __shared__ u16 lCT[128 * 136];

    const int tid = threadIdx.x;
    const int nwg = gridDim.x;               // 288
    const int logical = (blockIdx.x & 7) * (nwg >> 3) + (blockIdx.x >> 3);
    const int b = logical / 36;
    int t = logical % 36;
    int i0 = 0;
    while (t >= 8 - i0) { t -= 8 - i0; ++i0; }
    const int j0 = i0 + t;
    const int m0 = i0 * 128, n0 = j0 * 128;

    const u16* p = Spb + (long)logical * 32768;
    for (int c8 = tid; c8 < 2048; c8 += 256) {
        const uint4 a = *(const uint4*)(p + c8 * 8);
        const uint4 b2 = *(const uint4*)(p + 16384 + c8 * 8);
        u16 o[8];
        o[0] = f2bf(bf2f((u16)(a.x & 0xFFFF)) + bf2f((u16)(b2.x & 0xFFFF)));
        o[1] = f2bf(bf2f((u16)(a.x >> 16))    + bf2f((u16)(b2.x >> 16)));
        o[2] = f2bf(bf2f((u16)(a.y & 0xFFFF)) + bf2f((u16)(b2.y & 0xFFFF)));
        o[3] = f2bf(bf2f((u16)(a.y >> 16))    + bf2f((u16)(b2.y >> 16)));
        o[4] = f2bf(bf2f((u16)(a.z & 0xFFFF)) + bf2f((u16)(b2.z & 0xFFFF)));
        o[5] = f2bf(bf2f((u16)(a.z >> 16))    + bf2f((u16)(b2.z >> 16)));
        o[6] = f2bf(bf2f((u16)(a.w & 0xFFFF)) + bf2f((u16)(b2.w & 0xFFFF)));
        o[7] = f2bf(bf2f((u16)(a.w >> 16))    + bf2f((u16)(b2.w >> 16)));
        const int r_ = c8 >> 4, c0 = (c8 & 15) * 8;
        *(uint4*)(lC + r_ * 136 + c0) = *(const uint4*)o;
#pragma unroll
        for (int k = 0; k < 8; ++k) lCT[(c0 + k) * 136 + r_] = o[k];
    }
    __syncthreads();
    const int tk = tid >> 1, half = tid & 1;
    {
        u16* dp = S + (long)b * 1048576 + (long)(m0 + tk) * 1024 + n0 + half * 64;
        const u16* sp1 = lC + tk * 136 + half * 64;
#pragma unroll
        for (int i = 0; i < 8; ++i) ((uint4*)dp)[i] = ((const uint4*)sp1)[i];
    }
    if (i0 != j0) {
        u16* dp = S + (long)b * 1048576 + (long)(n0 + tk) * 1024 + m0 + half * 64;
        const u16* sp2 = lCT + tk * 136 + half * 64;
#pragma unroll
        for (int i = 0; i < 8; ++i) ((uint4*)dp)[i] = ((const uint4*)sp2)[i];
    }
}

// ---------------- 128x128 GEMM, BK=32, batched, bf16 out (wfinT) -----------------
__global__ __launch_bounds__(256) void k_g128(
    const u16* __restrict__ A, long Ab, const u16* __restrict__ Bt, long Bs,
    u16* __restrict__ C, long Cb, int K, int MT, int NT)
{
    __shared__ u16 sm[8192];
    __shared__ u16 lC[128 * 136];

    const int tid = threadIdx.x;
    const int wid = tid >> 6, lane = tid & 63;
    const int wr = wid >> 1, wc = wid & 1;
    const int fr = lane & 15, sl = lane >> 4;

    const int nwg = gridDim.x;
    const int logical = (blockIdx.x & 7) * (nwg >> 3) + (blockIdx.x >> 3);

    const int b = logical / (MT * NT);
    const int r = logical % (MT * NT);
    const int i0 = r / NT, j0 = r % NT;
    const int m0 = i0 * 128, n0 = j0 * 128;
    const u16* Abp = A + (long)b * Ab;
    const u16* Bbp = Bt + (long)b * Bs;
    u16* Cbp = C + (long)b * Cb;

    const int srow = lane >> 2;
    const int sslot = lane & 3;

    f32x4 acc[4][4];
#pragma unroll
    for (int i = 0; i < 4; ++i)
#pragma unroll
        for (int j = 0; j < 4; ++j) acc[i][j] = (f32x4){0.f, 0.f, 0.f, 0.f};

    for (int kt = 0; kt < K; kt += 32) {
        __syncthreads();
#pragma unroll
        for (int i = 0; i < 2; ++i) {
            const int row = wid * 32 + i * 16 + srow;
            const int swz = (sslot ^ ((row >> 1) & 3)) << 3;
            const u16* ga = Abp + (long)(m0 + row) * K + kt + swz;
            const u16* gb = Bbp + (long)(n0 + row) * K + kt + swz;
            __builtin_amdgcn_global_load_lds((gp_t)ga, (lp_t)(sm + (wid * 2 + i) * 512), 16, 0, 0);
            __builtin_amdgcn_global_load_lds((gp_t)gb, (lp_t)(sm + 4096 + (wid * 2 + i) * 512), 16, 0, 0);
        }
        __syncthreads();
        bf16x8 af[4], bfr[4];
#pragma unroll
        for (int mi = 0; mi < 4; ++mi) {
            const int row = wr * 64 + mi * 16 + fr;
            af[mi] = *(const bf16x8*)(sm + row * 32 + ((sl ^ ((row >> 1) & 3)) << 3));
        }
#pragma unroll
        for (int ni = 0; ni < 4; ++ni) {
            const int row = wc * 64 + ni * 16 + fr;
            bfr[ni] = *(const bf16x8*)(sm + 4096 + row * 32 + ((sl ^ ((row >> 1) & 3)) << 3));
        }
#pragma unroll
        for (int mi = 0; mi < 4; ++mi)
#pragma unroll
            for (int ni = 0; ni < 4; ++ni)
                acc[mi][ni] = __builtin_amdgcn_mfma_f32_16x16x32_bf16(af[mi], bfr[ni], acc[mi][ni], 0, 0, 0);
    }
    __syncthreads();

#pragma unroll
    for (int mi = 0; mi < 4; ++mi)
#pragma unroll
        for (int ni = 0; ni < 4; ++ni) {
            const int ch = wc * 64 + ni * 16 + fr;
            const int tk = wr * 64 + mi * 16 + sl * 4;
#pragma unroll
            for (int rr = 0; rr < 4; ++rr)
                lC[(tk + rr) * 136 + ch] = f2bf(acc[mi][ni][rr]);
        }
    __syncthreads();
    {
        const int tk = tid >> 1, half = tid & 1;
        const u16* sp = lC + tk * 136 + half * 64;
        u16* dp = Cbp + (long)(m0 + tk) * 1024 + n0 + half * 64;
#pragma unroll
        for (int i = 0; i < 8; ++i) ((uint4*)dp)[i] = ((const uint4*)sp)[i];
    }
}

// ---------------- 256x256 GEMM, BK=64, K=1024, batched; EPI 0=bf16, 1=f32+bias ---
template<int EPI>
__global__ __launch_bounds__(512, 2) void k_gemm256(
    const u16* __restrict__ A, long Ab, const u16* __restrict__ Bt, long Bs,
    int MT, int NT,
    u16* __restrict__ cB, float* __restrict__ cF, long Cb, const float* __restrict__ bias)
{
    __shared__ uint4 smem4[8704];
    u16* sm = (u16*)smem4;

    const int tid = threadIdx.x;
    const int wid = tid >> 6, lane = tid & 63;
    const int wr = wid >> 2, wc = wid & 3;
    const int fr = lane & 15, sl = lane >> 4;

    const int nwg = gridDim.x;
    const int logical = (blockIdx.x & 7) * (nwg >> 3) + (blockIdx.x >> 3);
    const int b = logical / (MT * NT);
    const int rem = logical % (MT * NT);
    const int mt = rem / NT, nt = rem % NT;
    const long m0 = (long)mt * 256;
    const int n0 = nt * 256;

    const int srow = wid * 32 + (lane >> 2);
    const int kswz = (((lane & 3) ^ ((srow >> 1) & 3)) << 3);
    const u16* gA = A + (long)b * Ab + (m0 + srow) * 1024L + kswz;
    const u16* gB = Bt + (long)b * Bs + ((long)n0 + srow) * 1024L + kswz;
    const int ldst = wid * 1024;

    const int fxor = ((sl ^ ((fr >> 1) & 3)) << 3);
    const int aBase = (wr * 128 + fr) * 32 + fxor;
    const int bBase = 32768 + (wc * 64 + fr) * 32 + fxor;

    f32x4 acc[8][4];
#pragma unroll
    for (int i = 0; i < 8; ++i)
#pragma unroll
        for (int j = 0; j < 4; ++j) acc[i][j] = (f32x4){0.f, 0.f, 0.f, 0.f};

#define STAGE_A(d, kh, ts) do { \
    const u16* g_ = gA + (ts) * 64 + (kh) * 32; \
    u16* l_ = sm + (d) * 16384 + (kh) * 8192 + ldst; \
    __builtin_amdgcn_global_load_lds((gp_t)g_, (lp_t)l_, 16, 0, 0); \
    __builtin_amdgcn_global_load_lds((gp_t)(g_ + 16 * 1024), (lp_t)(l_ + 512), 16, 0, 0); \
} while (0)
#define STAGE_B(d, kh, ts) do { \
    const u16* g_ = gB + (ts) * 64 + (kh) * 32; \
    u16* l_ = sm + 32768 + (d) * 16384 + (kh) * 8192 + ldst; \
    __builtin_amdgcn_global_load_lds((gp_t)g_, (lp_t)l_, 16, 0, 0); \
    __builtin_amdgcn_global_load_lds((gp_t)(g_ + 16 * 1024), (lp_t)(l_ + 512), 16, 0, 0); \
} while (0)

    STAGE_A(0, 0, 0); STAGE_B(0, 0, 0);
    STAGE_A(0, 1, 0); STAGE_B(0, 1, 0);
    STAGE_A(1, 0, 1); STAGE_B(1, 0, 1);
    asm volatile("s_waitcnt vmcnt(8)" ::: "memory");
    __builtin_amdgcn_s_barrier();

    bf16x8 afX[4], afY[4], bfX[4], bfY[4];
#pragma unroll
    for (int ni = 0; ni < 4; ++ni) bfX[ni] = *(const bf16x8*)(sm + bBase + ni * 512);
#pragma unroll
    for (int mi = 0; mi < 4; ++mi) afX[mi] = *(const bf16x8*)(sm + aBase + mi * 512);

#pragma unroll 2
    for (int T = 0; T < 16; ++T) {
        const int d = T & 1;
        const int t1 = (T + 1 < 16) ? T + 1 : 15;
        const int t2 = (T + 2 < 16) ? T + 2 : 15;
        const int base = d * 16384;
        const int nbase = (d ^ 1) * 16384;

#pragma unroll
        for (int mi = 0; mi < 4; ++mi)
            afY[mi] = *(const bf16x8*)(sm + aBase + (4 + mi) * 512 + base);
        STAGE_A(d ^ 1, 1, t1);
        asm volatile("s_waitcnt vmcnt(6)" ::: "memory");
        __builtin_amdgcn_s_barrier();
        __builtin_amdgcn_s_setprio(1);
#pragma unroll
        for (int mi = 0; mi < 4; ++mi)
#pragma unroll
            for (int ni = 0; ni < 4; ++ni)
                acc[mi][ni] = __builtin_amdgcn_mfma_f32_16x16x32_bf16(afX[mi], bfX[ni], acc[mi][ni], 0, 0, 0);
        __builtin_amdgcn_s_setprio(0);
        __builtin_amdgcn_s_barrier();

#pragma unroll
        for (int ni = 0; ni < 4; ++ni)
            bfY[ni] = *(const bf16x8*)(sm + bBase + ni * 512 + base + 8192);
#pragma unroll
        for (int mi = 0; mi < 4; ++mi)
            afX[mi] = *(const bf16x8*)(sm + aBase + mi * 512 + base + 8192);
        STAGE_B(d ^ 1, 1, t1);
        __builtin_amdgcn_s_barrier();
        __builtin_amdgcn_s_setprio(1);
#pragma unroll
        for (int mi = 0; mi < 4; ++mi)
#pragma unroll
            for (int ni = 0; ni < 4; ++ni)
                acc[mi + 4][ni] = __builtin_amdgcn_mfma_f32_16x16x32_bf16(afY[mi], bfX[ni], acc[mi + 4][ni], 0, 0, 0);
        __builtin_amdgcn_s_setprio(0);
        __builtin_amdgcn_s_barrier();

#pragma unroll
        for (int mi = 0; mi < 4; ++mi)
            afY[mi] = *(const bf16x8*)(sm + aBase + (4 + mi) * 512 + base + 8192);
        STAGE_A(d, 0, t2);
        asm volatile("s_waitcnt vmcnt(6)" ::: "memory");
        __builtin_amdgcn_s_barrier();
        __builtin_amdgcn_s_setprio(1);
#pragma unroll
        for (int mi = 0; mi < 4; ++mi)
#pragma unroll
            for (int ni = 0; ni < 4; ++ni)
                acc[mi][ni] = __builtin_amdgcn_mfma_f32_16x16x32_bf16(afX[mi], bfY[ni], acc[mi][ni], 0, 0, 0);
        __builtin_amdgcn_s_setprio(0);
        __builtin_amdgcn_s_barrier();

#pragma unroll
        for (int ni = 0; ni < 4; ++ni)
            bfX[ni] = *(const bf16x8*)(sm + bBase + ni * 512 + nbase);
#pragma unroll
        for (int mi = 0; mi < 4; ++mi)
            afX[mi] = *(const bf16x8*)(sm + aBase + mi * 512 + nbase);
        STAGE_B(d, 0, t2);
        __builtin_amdgcn_s_barrier();
        __builtin_amdgcn_s_setprio(1);
#pragma unroll
        for (int mi = 0; mi < 4; ++mi)
#pragma unroll
            for (int ni = 0; ni < 4; ++ni)
                acc[mi + 4][ni] = __builtin_amdgcn_mfma_f32_16x16x32_bf16(afY[mi], bfY[ni], acc[mi + 4][ni], 0, 0, 0);
        __builtin_amdgcn_s_setprio(0);
        __builtin_amdgcn_s_barrier();
    }
#undef STAGE_A
#undef STAGE_B
    asm volatile("s_waitcnt vmcnt(0)" ::: "memory");
    __syncthreads();

    if (EPI == 0) {
        u16* cbase = cB + (long)b * Cb;
        u16* piece = sm + wid * 8704;
#pragma unroll
        for (int mi = 0; mi < 8; ++mi)
#pragma unroll
            for (int ni = 0; ni < 4; ++ni) {
                const int ch = ni * 16 + fr;
                const int tk = mi * 16 + sl * 4;
#pragma unroll
                for (int rr = 0; rr < 4; ++rr)
                    piece[(tk + rr) * 68 + ch] = f2bf(acc[mi][ni][rr]);
            }
        __syncthreads();
#pragma unroll
        for (int i = 0; i < 32; ++i) {
            const int chunk = i * 512 + tid;
            const int row = chunk >> 4, c8 = chunk & 15;
            const int p = row >> 7, tk = row & 127;
            const int wrp = p >> 2, wcp = p & 3;
            const uint2 v = *(const uint2*)(sm + p * 8704 + tk * 68 + c8 * 4);
            *(uint2*)(cbase + (m0 + wrp * 128 + tk) * 1024L + n0 + wcp * 64 + c8 * 4) = v;
        }
    } else {
        float* cbase = cF + (long)b * Cb;
        float bi[4];
#pragma unroll
        for (int ni = 0; ni < 4; ++ni) bi[ni] = bias[n0 + wc * 64 + ni * 16 + fr];
#pragma unroll
        for (int pass = 0; pass < 2; ++pass) {
            float* pieceF = (float*)smem4 + wid * 4352;
            if (pass) __syncthreads();
#pragma unroll
            for (int mi2 = 0; mi2 < 4; ++mi2) {
                const int mi = pass * 4 + mi2;
#pragma unroll
                for (int ni = 0; ni < 4; ++ni) {
                    const int ch = ni * 16 + fr;
                    const int tk = mi2 * 16 + sl * 4;
#pragma unroll
                    for (int rr = 0; rr < 4; ++rr)
                        pieceF[(tk + rr) * 68 + ch] = acc[mi][ni][rr] + bi[ni];
                }
            }
            __syncthreads();
#pragma unroll
            for (int i = 0; i < 16; ++i) {
                const int chunk = i * 512 + tid;
                const int row = chunk >> 4, c4 = chunk & 15;
                const int p = row >> 6, tk = row & 63;
                const int wrp = p >> 2, wcp = p & 3;
                const float4 v = *(const float4*)((float*)smem4 + p * 4352 + tk * 68 + c4 * 4);
                *(float4*)(cbase + (m0 + wrp * 128 + pass * 64 + tk) * 1024L + n0 + wcp * 64 + c4 * 4) = v;
            }
        }
    }
}

// ---------------- gram partials per (b,h,kseg): 64x64 Gram + 128 row-dots --------
__global__ __launch_bounds__(256) void k_gram2p(
    const u16* __restrict__ wqT, const u16* __restrict__ Ut,
    float* __restrict__ g2p, float* __restrict__ sq2p)
{
    __shared__ u16 lQ[64 * 256];
    __shared__ u16 lK[64 * 256];

    const int blk = blockIdx.x;           // bh*4 + seg
    const int seg = blk & 3, bh = blk >> 2;
    const int b = bh >> 4, h = bh & 15;
    const int tid = threadIdx.x;
    const int wid = tid >> 6, lane = tid & 63;

    {
        const int r2 = lane >> 5, slot = lane & 31;
        const int rbase = wid * 16;
#pragma unroll
        for (int i = 0; i < 8; ++i) {
            const int r = rbase + i * 2 + r2;
            const int col = seg * 256 + ((slot ^ (r & 7)) << 3);
            const u16* gq = wqT + (long)(h * 64 + r) * 1024 + col;
            const u16* gk = Ut + ((long)b * 2048 + 1024 + h * 64 + r) * 1024 + col;
            __builtin_amdgcn_global_load_lds((gp_t)gq, (lp_t)(lQ + (rbase + i * 2) * 256), 16, 0, 0);
            __builtin_amdgcn_global_load_lds((gp_t)gk, (lp_t)(lK + (rbase + i * 2) * 256), 16, 0, 0);
        }
    }
    __syncthreads();

    {
        const int row = tid >> 1, half = tid & 1;
        const int j = (row < 64) ? (h * 64 + row) : (1024 + h * 64 + (row - 64));
        const u16* pa = wqT + (long)j * 1024 + seg * 256 + half * 128;
        const u16* pb = Ut + ((long)b * 2048 + j) * 1024 + seg * 256 + half * 128;
        float s = 0.f;
#pragma unroll 4
        for (int i = 0; i < 16; ++i) {
            const uint4 a = *(const uint4*)(pa + i * 8);
            const uint4 bv = *(const uint4*)(pb + i * 8);
            s += bf2f((u16)(a.x & 0xFFFF)) * bf2f((u16)(bv.x & 0xFFFF));
            s += bf2f((u16)(a.x >> 16))    * bf2f((u16)(bv.x >> 16));
            s += bf2f((u16)(a.y & 0xFFFF)) * bf2f((u16)(bv.y & 0xFFFF));
            s += bf2f((u16)(a.y >> 16))    * bf2f((u16)(bv.y >> 16));
            s += bf2f((u16)(a.z & 0xFFFF)) * bf2f((u16)(bv.z & 0xFFFF));
            s += bf2f((u16)(a.z >> 16))    * bf2f((u16)(bv.z >> 16));
            s += bf2f((u16)(a.w & 0xFFFF)) * bf2f((u16)(bv.w & 0xFFFF));
            s += bf2f((u16)(a.w >> 16))    * bf2f((u16)(bv.w >> 16));
        }
        s += __shfl_xor(s, 1);
        if (half == 0) sq2p[(long)blk * 128 + row] = s;
    }

    const int fr = lane & 15, sl = lane >> 4;
    f32x4 acc[4];
#pragma unroll
    for (int i = 0; i < 4; ++i) acc[i] = (f32x4){0.f, 0.f, 0.f, 0.f};
#pragma unroll
    for (int ks = 0; ks < 8; ++ks) {
        const int ra = wid * 16 + fr;
        const bf16x8 a = *(const bf16x8*)(lQ + ra * 256 + (((ks * 4 + sl) ^ (ra & 7)) << 3));
#pragma unroll
        for (int ni = 0; ni < 4; ++ni) {
            const int rb = ni * 16 + fr;
            const bf16x8 bb = *(const bf16x8*)(lK + rb * 256 + (((ks * 4 + sl) ^ (rb & 7)) << 3));
            acc[ni] = __builtin_amdgcn_mfma_f32_16x16x32_bf16(a, bb, acc[ni], 0, 0, 0);
        }
    }
    float* gp = g2p + (long)blk * 4096;
#pragma unroll
    for (int ni = 0; ni < 4; ++ni)
#pragma unroll
        for (int rr = 0; rr < 4; ++rr)
            gp[(wid * 16 + sl * 4 + rr) * 64 + ni * 16 + fr] = acc[ni][rr];
}

// ---------------- fused: reduce gram partials + softmax + wmix -------------------
__global__ __launch_bounds__(256) void k_swmix(
    const float* __restrict__ g2p, const float* __restrict__ sq2p,
    const float* __restrict__ temperature,
    const u16* __restrict__ wpT, u16* __restrict__ wmix)
{
    __shared__ u16 lA[64 * 72];
    __shared__ u16 lB[256 * 64];

    const int blk = blockIdx.x;
    const int nseg = blk & 3, bh = blk >> 2;
    const int b = bh >> 4, h = bh & 15;
    const int tid = threadIdx.x;
    const int wid = tid >> 6, lane = tid & 63;
    const int fr = lane & 15, sl = lane >> 4;

#pragma unroll
    for (int i = 0; i < 8; ++i) {
        const int cc = wid * 8 + i;
        const int row = cc * 8 + (lane >> 3);
        const int slot = lane & 7;
        const u16* g = wpT + (long)(nseg * 256 + row) * 1024 + h * 64 + ((slot ^ (row & 7)) << 3);
        __builtin_amdgcn_global_load_lds((gp_t)g, (lp_t)(lB + cc * 512), 16, 0, 0);
    }

    {
        const int e = lane;
        const float* sp = sq2p + (long)bh * 512;
        float sqk = 0.f;
#pragma unroll
        for (int s = 0; s < 4; ++s) sqk += sp[s * 128 + 64 + e];
        const float rk = 1.f / fmaxf(sqrtf(sqk), 1e-12f);
        const float temp = temperature[h];
        const float* gp = g2p + (long)bh * 16384;
#pragma unroll 2
        for (int i = 0; i < 16; ++i) {
            const int d = wid * 16 + i;
            float raw = 0.f, sqq = 0.f;
#pragma unroll
            for (int s = 0; s < 4; ++s) {
                raw += gp[s * 4096 + d * 64 + e];
                sqq += sp[s * 128 + d];
            }
            const float rq = 1.f / fmaxf(sqrtf(sqq), 1e-12f);
            const float v = raw * rq * rk * temp;
            float mx = v;
#pragma unroll
            for (int o = 32; o; o >>= 1) mx = fmaxf(mx, __shfl_xor(mx, o));
            const float p = __expf(v - mx);
            float sum = p;
#pragma unroll
            for (int o = 32; o; o >>= 1) sum += __shfl_xor(sum, o);
            lA[e * 72 + d] = f2bf(p / sum);
        }
    }
    __syncthreads();

    f32x4 acc[4][4];
#pragma unroll
    for (int i = 0; i < 4; ++i)
#pragma unroll
        for (int j = 0; j < 4; ++j) acc[i][j] = (f32x4){0.f, 0.f, 0.f, 0.f};

#pragma unroll
    for (int ks = 0; ks < 2; ++ks) {
        bf16x8 a[4], bb[4];
#pragma unroll
        for (int mi = 0; mi < 4; ++mi)
            a[mi] = *(const bf16x8*)(lA + (mi * 16 + fr) * 72 + ks * 32 + sl * 8);
#pragma unroll
        for (int ni = 0; ni < 4; ++ni) {
            const int rb = wid * 64 + ni * 16 + fr;
            bb[ni] = *(const bf16x8*)(lB + rb * 64 + (((ks * 4 + sl) ^ (rb & 7)) << 3));
        }
#pragma unroll
        for (int mi = 0; mi < 4; ++mi)
#pragma unroll
            for (int ni = 0; ni < 4; ++ni)
                acc[mi][ni] = __builtin_amdgcn_mfma_f32_16x16x32_bf16(a[mi], bb[ni], acc[mi][ni], 0, 0, 0);
    }

    u16* dst = wmix + ((long)b << 20);
#pragma unroll
    for (int mi = 0; mi < 4; ++mi)
#pragma unroll
        for (int ni = 0; ni < 4; ++ni) {
            const int cout = nseg * 256 + wid * 64 + ni * 16 + fr;
            const int e0 = mi * 16 + sl * 4;
            ushort4 w;
            w.x = f2bf(acc[mi][ni][0]); w.y = f2bf(acc[mi][ni][1]);
            w.z = f2bf(acc[mi][ni][2]); w.w = f2bf(acc[mi][ni][3]);
            *(ushort4*)(dst + (long)cout * 1024 + h * 64 + e0) = w;
        }
}

// ---------------- launch ----------------
extern "C" void kernel_launch(void* const* d_in, const int* in_sizes, int n_in,
                              void* d_out, int out_size, void* d_ws, size_t ws_size,
                              hipStream_t stream) {
    const float* x = (const float*)d_in[0];
    const float* w_qkv = (const float*)d_in[1];
    const float* temperature = (const float*)d_in[2];
    const float* w_proj = (const float*)d_in[3];
    const float* b_proj = (const float*)d_in[4];
    float* out = (float*)d_out;
    char* ws = (char*)d_ws;

    u16* wqT    = (u16*)(ws);                       //   6,291,456 B [3072][1024] bf16
    u16* wpT    = (u16*)(ws + 6291456);             //   2,097,152 B [1024][1024] bf16
    u16* wvb    = (u16*)(ws + 8388608);             //   2,097,152 B [1024][1024] bf16
    u16* xt     = (u16*)(ws + 10485760);            //  67,108,864 B [32768][1024] bf16
    u16* xc     = (u16*)(ws + 77594624);            //  67,108,864 B [8][1024][4096] bf16
    u16* S      = (u16*)(ws + 144703488);           //  16,777,216 B [8][1024][1024] bf16
    u16* Spb    = (u16*)(ws + 161480704);           //  18,874,368 B [576][128][128] bf16 (dead after k_sred)
    u16* Ut     = (u16*)(ws + 161480704);           //  33,554,432 B (overlays Spb after k_sred)
    float* g2p  = (float*)(ws + 195035136);         //   8,388,608 B [512][64][64] f32
    float* sq2p = (float*)(ws + 203423744);         //     262,144 B [512][128] f32
    u16* wmix   = (u16*)(ws + 204734464);           //  16,777,216 B
    u16* wfinT  = (u16*)(ws + 221511680);           //  16,777,216 B

    k_prepack<<<9728, 256, 0, stream>>>(x, w_qkv, w_proj, xt, xc, wqT, wpT, wvb);
    // S partials: 8 x 36 tri x 2 ksegs (K=2048 each), bf16 out
    k_g128p<<<576, 256, 0, stream>>>(xc, Spb);
    k_sred<<<288, 256, 0, stream>>>(Spb, S);
    // Ut_b = wqT(0..2048) @ S_b (S symmetric): 8 x 8 x 4 = 256 blocks, 256^2 tiles
    k_gemm256<0><<<256, 512, 0, stream>>>(wqT, 0L, S, 1048576L, 8, 4, Ut, nullptr, 2097152L, nullptr);
    k_gram2p<<<512, 256, 0, stream>>>(wqT, Ut, g2p, sq2p);
    k_swmix<<<512, 256, 0, stream>>>(g2p, sq2p, temperature, wpT, wmix);
    // wfinT_b[cout][cin] = sum_e wmix_b[cout][e] * wvb[cin][e]
    k_g128<<<512, 256, 0, stream>>>(wmix, 1048576L, wvb, 0L, wfinT, 1048576L, 1024, 8, 8);
    // out = xt @ wfinT_b^T + bias: 8 x 16 x 4 = 512 blocks, 256^2 tiles
    k_gemm256<1><<<512, 512, 0, stream>>>(xt, 4194304L, wfinT, 1048576L, 16, 4, nullptr, out, 4194304L, b_proj);
}